// Round 7
// baseline (203.491 us; speedup 1.0000x reference)
//
#include <hip/hip_runtime.h>
#include <hip/hip_bf16.h>
#include <stdint.h>

using bf16 = __bf16;
using bf16x4 = __attribute__((ext_vector_type(4))) __bf16;
using bf16x8 = __attribute__((ext_vector_type(8))) __bf16;
using f32x4 = __attribute__((ext_vector_type(4))) float;

static constexpr int SEQ = 2048;
static constexpr int NDIM = 1024;
static constexpr int NHEAD = 16;
static constexpr int HD = 64;
// fold softmax scale and log2(e) into Q so scores are already in log2 domain
static constexpr float QSCALE = 0.125f * 1.4426950408889634f;

__device__ __forceinline__ void load_lds16(const void* g, void* l) {
  __builtin_amdgcn_global_load_lds(
      (const __attribute__((address_space(1))) void*)g,
      (__attribute__((address_space(3))) void*)l, 16, 0, 0);
}

// ---------------- fp32 -> bf16 convert (4 elems/thread) ----------------
__global__ __launch_bounds__(256) void k_cvt(const float* __restrict__ in,
                                             bf16* __restrict__ out, int n) {
  int i = (blockIdx.x * 256 + threadIdx.x) * 4;
  if (i >= n) return;
  float4 v = *(const float4*)(in + i);
  bf16x4 o;
  o[0] = (bf16)v.x; o[1] = (bf16)v.y; o[2] = (bf16)v.z; o[3] = (bf16)v.w;
  *(bf16x4*)(out + i) = o;
}

// ---------------- W (K x N) fp32 -> WT (N x K) bf16 ----------------
__global__ __launch_bounds__(256) void k_transpose(const float* __restrict__ W,
                                                   bf16* __restrict__ WT,
                                                   int K, int N) {
  __shared__ float t[32][33];
  int n0 = blockIdx.x * 32, k0 = blockIdx.y * 32;
  int tx = threadIdx.x & 31, ty = threadIdx.x >> 5;  // 32 x 8
#pragma unroll
  for (int i = 0; i < 4; i++)
    t[ty + 8 * i][tx] = W[(size_t)(k0 + ty + 8 * i) * N + n0 + tx];
  __syncthreads();
#pragma unroll
  for (int i = 0; i < 4; i++)
    WT[(size_t)(n0 + ty + 8 * i) * K + k0 + tx] = (bf16)t[tx][ty + 8 * i];
}

// ---------------- bf16 GEMM: C = A(MxK) @ BT(NxK)^T ----------------
// MODE 2: C fp32 + bias                           (output projection)
// MODE 3: fused QKV: col<1024 -> Q bf16 * scale; col in [1024,1088) -> K bf16
//         (C2); col >= 1088 -> V bf16 stored transposed per batch (C3)
template <int BM, int BN, int WM, int WN, int MODE>
__global__ __launch_bounds__(256) void k_gemm(const bf16* __restrict__ A,
                                              const bf16* __restrict__ BT,
                                              void* __restrict__ C,
                                              void* __restrict__ C2,
                                              void* __restrict__ C3,
                                              const float* __restrict__ bias,
                                              int M, int N, int K, float scale) {
  __shared__ __align__(16) char As[BM * 128];
  __shared__ __align__(16) char Bs[BN * 128];
  const int lane = threadIdx.x & 63;
  const int wv = threadIdx.x >> 6;
  constexpr int NWC = BN / WN;
  const int wr = wv / NWC, wc = wv % NWC;
  const int g = lane >> 4, l15 = lane & 15;
  const int m0 = blockIdx.y * BM, n0 = blockIdx.x * BN;
  constexpr int MI = WM / 16, NI = WN / 16;

  f32x4 acc[MI][NI] = {};

  const int srow = lane >> 3;   // staging row within 8-row chunk
  const int c16 = lane & 7;     // staging 16B-column within row

  for (int kt = 0; kt < K; kt += 64) {
    // stage A tile (BM x 64 bf16), XOR-swizzled source, linear LDS dest
#pragma unroll
    for (int j = wv; j < BM / 8; j += 4) {
      int row = j * 8 + srow;
      const char* src = (const char*)A + (size_t)(m0 + row) * (K * 2) + kt * 2 +
                        ((c16 ^ (row & 7)) << 4);
      load_lds16(src, As + j * 1024);
    }
#pragma unroll
    for (int j = wv; j < BN / 8; j += 4) {
      int row = j * 8 + srow;
      const char* src = (const char*)BT + (size_t)(n0 + row) * (K * 2) + kt * 2 +
                        ((c16 ^ (row & 7)) << 4);
      load_lds16(src, Bs + j * 1024);
    }
    __syncthreads();
#pragma unroll
    for (int kk = 0; kk < 2; kk++) {
      bf16x8 af[MI], bfr[NI];
#pragma unroll
      for (int mi = 0; mi < MI; mi++) {
        int row = wr * WM + mi * 16 + l15;
        af[mi] = *(const bf16x8*)(As + row * 128 + (((kk * 4 + g) ^ (row & 7)) << 4));
      }
#pragma unroll
      for (int ni = 0; ni < NI; ni++) {
        int row = wc * WN + ni * 16 + l15;
        bfr[ni] = *(const bf16x8*)(Bs + row * 128 + (((kk * 4 + g) ^ (row & 7)) << 4));
      }
#pragma unroll
      for (int mi = 0; mi < MI; mi++)
#pragma unroll
        for (int ni = 0; ni < NI; ni++)
          acc[mi][ni] = __builtin_amdgcn_mfma_f32_16x16x32_bf16(af[mi], bfr[ni],
                                                                acc[mi][ni], 0, 0, 0);
    }
    __syncthreads();
  }

#pragma unroll
  for (int mi = 0; mi < MI; mi++)
#pragma unroll
    for (int ni = 0; ni < NI; ni++) {
      int col = n0 + wc * WN + ni * 16 + l15;
      int rowb = m0 + wr * WM + mi * 16 + g * 4;
      if (MODE == 2) {
        float bv = bias[col];
#pragma unroll
        for (int r = 0; r < 4; r++)
          ((float*)C)[(size_t)(rowb + r) * N + col] = acc[mi][ni][r] + bv;
      } else {  // MODE 3: fused QKV epilogue
        if (col < 1024) {
#pragma unroll
          for (int r = 0; r < 4; r++)
            ((bf16*)C)[(size_t)(rowb + r) * 1024 + col] =
                (bf16)(acc[mi][ni][r] * scale);
        } else if (col < 1088) {
#pragma unroll
          for (int r = 0; r < 4; r++)
            ((bf16*)C2)[(size_t)(rowb + r) * 64 + (col - 1024)] =
                (bf16)acc[mi][ni][r];
        } else {
#pragma unroll
          for (int r = 0; r < 4; r++) {
            int m = rowb + r;
            ((bf16*)C3)[((size_t)((m >> 11) * 64 + (col - 1088))) * 2048 +
                        (m & 2047)] = (bf16)acc[mi][ni][r];
          }
        }
      }
    }
}

// ---------------- fused attention (4 heads/wave, K/V software pipeline) -----
// Q: (B*SEQ, 1024) bf16 pre-scaled by SCALE*log2(e); K: (B*SEQ, 64) bf16;
// VT: (B, 64, SEQ) bf16; O: (B*SEQ, 1024) bf16.
// grid = B * (H/4) * (SEQ/16) = 1024 blocks; block = 4 waves = 4 kv-quarters.
// Each wave: 16 q-rows x 4 heads over a quarter of KV; K/V fragments loaded
// ONCE per tile and reused by all 4 heads.
// Pipeline: V(t) loads issued at tile top (hide under QK+exp2); K(t+1)
// prefetched into the alternate register set (hide across the whole tile).
// Named A/B sets + unrolled double-body keep all indexing static (rule #20).
// REGISTER BUDGET (r4/r5 lesson): launch_bounds 2nd arg caps the UNIFIED
// VGPR+AGPR pool; (256,4)/(256,3) both forced in-loop scratch spills (489/172
// MB HBM scratch). (256,2)=256-cap is required. Live set now ~230 unified.
__global__ __launch_bounds__(256, 2) void k_attn(const bf16* __restrict__ Q,
                                                 const bf16* __restrict__ K,
                                                 const bf16* __restrict__ VT,
                                                 bf16* __restrict__ O) {
  __shared__ __align__(16) char smem[36864];
  int bid = blockIdx.x;
  int q16 = bid & 127;
  int hg = (bid >> 7) & 3;
  int b = bid >> 9;
  int wv = threadIdx.x >> 6, lane = threadIdx.x & 63;
  int g = lane >> 4, l15 = lane & 15;
  int q0 = q16 * 16;

  const char* qbase =
      (const char*)Q + ((size_t)(b * SEQ + q0 + l15) * NDIM + hg * 4 * HD) * 2;
  bf16x8 aq0[4], aq1[4];
#pragma unroll
  for (int hh = 0; hh < 4; hh++) {
    aq0[hh] = *(const bf16x8*)(qbase + hh * 128 + g * 16);
    aq1[hh] = *(const bf16x8*)(qbase + hh * 128 + 64 + g * 16);
  }

  const char* kbase = (const char*)K + (size_t)(b * SEQ) * (HD * 2);
  const char* vbase = (const char*)VT + (size_t)(b * HD) * (SEQ * 2);

  f32x4 acc[4][4] = {};
  float lsum[4][4] = {};

  bf16* Pw = (bf16*)(smem + wv * 4 * 2304);  // this wave's 4 P tiles [16][72]

  const int kvbeg = wv * (SEQ / 4);

  // K fragment double buffer: [c*2+half]
  bf16x8 kA[8], kB[8];
#pragma unroll
  for (int c = 0; c < 4; c++) {
    const char* kb = kbase + (size_t)(kvbeg + c * 16 + l15) * 128 + g * 16;
    kA[c * 2] = *(const bf16x8*)kb;
    kA[c * 2 + 1] = *(const bf16x8*)(kb + 64);
  }

  auto tile = [&](bf16x8* kc, bf16x8* kn, int kv0, bool pref) {
    // V(t) loads first: latency hides under QK + exp2
    bf16x8 vf[8];  // [kk*4+c]
#pragma unroll
    for (int kk = 0; kk < 2; kk++)
#pragma unroll
      for (int c = 0; c < 4; c++)
        vf[kk * 4 + c] =
            *(const bf16x8*)(vbase + (size_t)(c * 16 + l15) * (SEQ * 2) +
                             (kv0 + kk * 32 + g * 8) * 2);
    // prefetch K(t+1): latency hides across the whole tile
    if (pref) {
#pragma unroll
      for (int c = 0; c < 4; c++) {
        const char* kb =
            kbase + (size_t)(kv0 + 64 + c * 16 + l15) * 128 + g * 16;
        kn[c * 2] = *(const bf16x8*)kb;
        kn[c * 2 + 1] = *(const bf16x8*)(kb + 64);
      }
    }
    // QK^T + exp2 + P stash (lsum in fp32: no cvt-back on the chain)
#pragma unroll
    for (int c = 0; c < 4; c++) {
#pragma unroll
      for (int hh = 0; hh < 4; hh++) {
        f32x4 t = {};
        t = __builtin_amdgcn_mfma_f32_16x16x32_bf16(aq0[hh], kc[c * 2], t, 0, 0, 0);
        t = __builtin_amdgcn_mfma_f32_16x16x32_bf16(aq1[hh], kc[c * 2 + 1], t, 0, 0, 0);
        bf16* P = Pw + hh * 1152;
#pragma unroll
        for (int r = 0; r < 4; r++) {
          float p = __builtin_amdgcn_exp2f(t[r]);
          lsum[hh][r] += p;
          P[(g * 4 + r) * 72 + c * 16 + l15] = (bf16)p;
        }
      }
    }
    // PV: P fragments per kk, V from pre-issued registers
#pragma unroll
    for (int kk = 0; kk < 2; kk++) {
      bf16x8 pa[4];
#pragma unroll
      for (int hh = 0; hh < 4; hh++)
        pa[hh] = *(const bf16x8*)(Pw + hh * 1152 + l15 * 72 + kk * 32 + g * 8);
#pragma unroll
      for (int c = 0; c < 4; c++) {
#pragma unroll
        for (int hh = 0; hh < 4; hh++)
          acc[hh][c] = __builtin_amdgcn_mfma_f32_16x16x32_bf16(
              pa[hh], vf[kk * 4 + c], acc[hh][c], 0, 0, 0);
      }
    }
  };

#pragma unroll
  for (int t = 0; t < 8; t += 2) {
    tile(kA, kB, kvbeg + t * 64, true);
    tile(kB, kA, kvbeg + (t + 1) * 64, t + 2 < 8);
  }

  // reduce row sums across the 16 lanes of each row group
#pragma unroll
  for (int m = 1; m < 16; m <<= 1)
#pragma unroll
    for (int hh = 0; hh < 4; hh++)
#pragma unroll
      for (int r = 0; r < 4; r++) lsum[hh][r] += __shfl_xor(lsum[hh][r], m, 64);

  // merge kv-quarter partials through LDS in two half-rounds (2 heads each),
  // reusing the P region. Buffer: [3 waves][64 lanes][40 floats] = 30720 B.
  float* mb = (float*)smem;
  __syncthreads();
#pragma unroll
  for (int half = 0; half < 2; half++) {
    if (wv > 0) {
      float* dst = mb + ((size_t)(wv - 1) * 64 + lane) * 40;
#pragma unroll
      for (int hh = 0; hh < 2; hh++) {
        int h2 = half * 2 + hh;
#pragma unroll
        for (int c = 0; c < 4; c++)
#pragma unroll
          for (int r = 0; r < 4; r++) dst[hh * 20 + c * 4 + r] = acc[h2][c][r];
#pragma unroll
        for (int r = 0; r < 4; r++) dst[hh * 20 + 16 + r] = lsum[h2][r];
      }
    }
    __syncthreads();
    if (wv == 0) {
#pragma unroll
      for (int w = 0; w < 3; w++) {
        const float* src = mb + ((size_t)w * 64 + lane) * 40;
#pragma unroll
        for (int hh = 0; hh < 2; hh++) {
          int h2 = half * 2 + hh;
#pragma unroll
          for (int c = 0; c < 4; c++)
#pragma unroll
            for (int r = 0; r < 4; r++) acc[h2][c][r] += src[hh * 20 + c * 4 + r];
#pragma unroll
          for (int r = 0; r < 4; r++) lsum[h2][r] += src[hh * 20 + 16 + r];
        }
      }
    }
    __syncthreads();
  }
  if (wv == 0) {
#pragma unroll
    for (int hh = 0; hh < 4; hh++)
#pragma unroll
      for (int c = 0; c < 4; c++)
#pragma unroll
        for (int r = 0; r < 4; r++) {
          float o = acc[hh][c][r] / lsum[hh][r];
          O[(size_t)(b * SEQ + q0 + g * 4 + r) * NDIM + (hg * 4 + hh) * HD +
            c * 16 + l15] = (bf16)o;
        }
  }
}

extern "C" void kernel_launch(void* const* d_in, const int* in_sizes, int n_in,
                              void* d_out, int out_size, void* d_ws, size_t ws_size,
                              hipStream_t stream) {
  const float* x = (const float*)d_in[0];
  const float* Wq = (const float*)d_in[1];
  const float* Wk = (const float*)d_in[2];
  const float* Wv = (const float*)d_in[3];
  const float* Wp = (const float*)d_in[4];
  const float* bp = (const float*)d_in[5];
  float* out = (float*)d_out;

  size_t off = 0;
  char* wsb = (char*)d_ws;
  auto alloc = [&](size_t bytes) {
    char* p = wsb + off;
    off += bytes;
    return p;
  };
  bf16* x_bf = (bf16*)alloc((size_t)4096 * 1024 * 2);
  bf16* wqkvT = (bf16*)alloc((size_t)1152 * 1024 * 2);  // [WqT;WkT;WvT]
  bf16* wpT = (bf16*)alloc((size_t)1024 * 1024 * 2);
  bf16* Qb = (bf16*)alloc((size_t)4096 * 1024 * 2);
  bf16* Kb = (bf16*)alloc((size_t)4096 * 64 * 2);
  bf16* VTb = (bf16*)alloc((size_t)2 * 64 * 2048 * 2);
  bf16* AOb = (bf16*)alloc((size_t)4096 * 1024 * 2);

  k_cvt<<<4096, 256, 0, stream>>>(x, x_bf, 4096 * 1024);
  k_transpose<<<dim3(32, 32), 256, 0, stream>>>(Wq, wqkvT, 1024, 1024);
  k_transpose<<<dim3(2, 32), 256, 0, stream>>>(Wk, wqkvT + (size_t)1024 * 1024,
                                               1024, 64);
  k_transpose<<<dim3(2, 32), 256, 0, stream>>>(Wv, wqkvT + (size_t)1088 * 1024,
                                               1024, 64);
  k_transpose<<<dim3(32, 32), 256, 0, stream>>>(Wp, wpT, 1024, 1024);

  // fused Q/K/V projection: N = 1152 = 1024(Q) + 64(K) + 64(V)
  k_gemm<128, 128, 64, 64, 3><<<dim3(9, 32), 256, 0, stream>>>(
      x_bf, wqkvT, Qb, Kb, VTb, nullptr, 4096, 1152, 1024, QSCALE);

  k_attn<<<1024, 256, 0, stream>>>(Qb, Kb, VTb, AOb);

  // output projection + bias, fp32 out
  k_gemm<128, 128, 64, 64, 2><<<dim3(8, 32), 256, 0, stream>>>(
      AOb, wpT, out, nullptr, nullptr, bp, 4096, 1024, 1024, 1.0f);
}

// Round 8
// 135.678 us; speedup vs baseline: 1.4998x; 1.4998x over previous
//
#include <hip/hip_runtime.h>
#include <hip/hip_bf16.h>
#include <stdint.h>

using bf16 = __bf16;
using bf16x4 = __attribute__((ext_vector_type(4))) __bf16;
using bf16x8 = __attribute__((ext_vector_type(8))) __bf16;
using f32x4 = __attribute__((ext_vector_type(4))) float;
using f32x16 = __attribute__((ext_vector_type(16))) float;
using u32x2 = __attribute__((ext_vector_type(2))) unsigned int;

static constexpr int SEQ = 2048;
static constexpr int NDIM = 1024;
static constexpr int NHEAD = 16;
static constexpr int HD = 64;
// fold softmax scale and log2(e) into Q so scores are already in log2 domain
static constexpr float QSCALE = 0.125f * 1.4426950408889634f;

__device__ __forceinline__ void load_lds16(const void* g, void* l) {
  __builtin_amdgcn_global_load_lds(
      (const __attribute__((address_space(1))) void*)g,
      (__attribute__((address_space(3))) void*)l, 16, 0, 0);
}

// pack two fp32 -> one u32 of two bf16 (lo = a, hi = b)
__device__ __forceinline__ uint32_t pk2(float a, float b) {
  uint16_t ua = __builtin_bit_cast(uint16_t, (bf16)a);
  uint16_t ub = __builtin_bit_cast(uint16_t, (bf16)b);
  return (uint32_t)ua | ((uint32_t)ub << 16);
}

// ---------------- fp32 -> bf16 convert (4 elems/thread) ----------------
__global__ __launch_bounds__(256) void k_cvt(const float* __restrict__ in,
                                             bf16* __restrict__ out, int n) {
  int i = (blockIdx.x * 256 + threadIdx.x) * 4;
  if (i >= n) return;
  float4 v = *(const float4*)(in + i);
  bf16x4 o;
  o[0] = (bf16)v.x; o[1] = (bf16)v.y; o[2] = (bf16)v.z; o[3] = (bf16)v.w;
  *(bf16x4*)(out + i) = o;
}

// ---------------- W (K x N) fp32 -> WT (N x K) bf16 ----------------
__global__ __launch_bounds__(256) void k_transpose(const float* __restrict__ W,
                                                   bf16* __restrict__ WT,
                                                   int K, int N) {
  __shared__ float t[32][33];
  int n0 = blockIdx.x * 32, k0 = blockIdx.y * 32;
  int tx = threadIdx.x & 31, ty = threadIdx.x >> 5;  // 32 x 8
#pragma unroll
  for (int i = 0; i < 4; i++)
    t[ty + 8 * i][tx] = W[(size_t)(k0 + ty + 8 * i) * N + n0 + tx];
  __syncthreads();
#pragma unroll
  for (int i = 0; i < 4; i++)
    WT[(size_t)(n0 + ty + 8 * i) * K + k0 + tx] = (bf16)t[tx][ty + 8 * i];
}

// ---------------- bf16 GEMM: C = A(MxK) @ BT(NxK)^T ----------------
// MODE 2: C fp32 + bias                           (output projection)
// MODE 3: fused QKV: col<1024 -> Q bf16 * scale; col in [1024,1088) -> K bf16
//         (C2); col >= 1088 -> V bf16 stored transposed per batch (C3)
template <int BM, int BN, int WM, int WN, int MODE>
__global__ __launch_bounds__(256) void k_gemm(const bf16* __restrict__ A,
                                              const bf16* __restrict__ BT,
                                              void* __restrict__ C,
                                              void* __restrict__ C2,
                                              void* __restrict__ C3,
                                              const float* __restrict__ bias,
                                              int M, int N, int K, float scale) {
  __shared__ __align__(16) char As[BM * 128];
  __shared__ __align__(16) char Bs[BN * 128];
  const int lane = threadIdx.x & 63;
  const int wv = threadIdx.x >> 6;
  constexpr int NWC = BN / WN;
  const int wr = wv / NWC, wc = wv % NWC;
  const int g = lane >> 4, l15 = lane & 15;
  const int m0 = blockIdx.y * BM, n0 = blockIdx.x * BN;
  constexpr int MI = WM / 16, NI = WN / 16;

  f32x4 acc[MI][NI] = {};

  const int srow = lane >> 3;   // staging row within 8-row chunk
  const int c16 = lane & 7;     // staging 16B-column within row

  for (int kt = 0; kt < K; kt += 64) {
    // stage A tile (BM x 64 bf16), XOR-swizzled source, linear LDS dest
#pragma unroll
    for (int j = wv; j < BM / 8; j += 4) {
      int row = j * 8 + srow;
      const char* src = (const char*)A + (size_t)(m0 + row) * (K * 2) + kt * 2 +
                        ((c16 ^ (row & 7)) << 4);
      load_lds16(src, As + j * 1024);
    }
#pragma unroll
    for (int j = wv; j < BN / 8; j += 4) {
      int row = j * 8 + srow;
      const char* src = (const char*)BT + (size_t)(n0 + row) * (K * 2) + kt * 2 +
                        ((c16 ^ (row & 7)) << 4);
      load_lds16(src, Bs + j * 1024);
    }
    __syncthreads();
#pragma unroll
    for (int kk = 0; kk < 2; kk++) {
      bf16x8 af[MI], bfr[NI];
#pragma unroll
      for (int mi = 0; mi < MI; mi++) {
        int row = wr * WM + mi * 16 + l15;
        af[mi] = *(const bf16x8*)(As + row * 128 + (((kk * 4 + g) ^ (row & 7)) << 4));
      }
#pragma unroll
      for (int ni = 0; ni < NI; ni++) {
        int row = wc * WN + ni * 16 + l15;
        bfr[ni] = *(const bf16x8*)(Bs + row * 128 + (((kk * 4 + g) ^ (row & 7)) << 4));
      }
#pragma unroll
      for (int mi = 0; mi < MI; mi++)
#pragma unroll
        for (int ni = 0; ni < NI; ni++)
          acc[mi][ni] = __builtin_amdgcn_mfma_f32_16x16x32_bf16(af[mi], bfr[ni],
                                                                acc[mi][ni], 0, 0, 0);
    }
    __syncthreads();
  }

#pragma unroll
  for (int mi = 0; mi < MI; mi++)
#pragma unroll
    for (int ni = 0; ni < NI; ni++) {
      int col = n0 + wc * WN + ni * 16 + l15;
      int rowb = m0 + wr * WM + mi * 16 + g * 4;
      if (MODE == 2) {
        float bv = bias[col];
#pragma unroll
        for (int r = 0; r < 4; r++)
          ((float*)C)[(size_t)(rowb + r) * N + col] = acc[mi][ni][r] + bv;
      } else {  // MODE 3: fused QKV epilogue
        if (col < 1024) {
#pragma unroll
          for (int r = 0; r < 4; r++)
            ((bf16*)C)[(size_t)(rowb + r) * 1024 + col] =
                (bf16)(acc[mi][ni][r] * scale);
        } else if (col < 1088) {
#pragma unroll
          for (int r = 0; r < 4; r++)
            ((bf16*)C2)[(size_t)(rowb + r) * 64 + (col - 1024)] =
                (bf16)acc[mi][ni][r];
        } else {
#pragma unroll
          for (int r = 0; r < 4; r++) {
            int m = rowb + r;
            ((bf16*)C3)[((size_t)((m >> 11) * 64 + (col - 1088))) * 2048 +
                        (m & 2047)] = (bf16)acc[mi][ni][r];
          }
        }
      }
    }
}

// ------------- fused attention: 32x32 MFMA, in-register softmax (T12) -------
// Q: (B*SEQ, 1024) bf16 pre-scaled by SCALE*log2(e); K: (B*SEQ, 64) bf16;
// VT: (B, 64, SEQ) bf16; O: (B*SEQ, 1024) bf16.
// grid = B * (H/2) * (SEQ/32) = 1024 blocks; block = 4 waves = 4 kv-quarters.
// Wave: 32 q-rows x 2 heads over a kv quarter.
// Swapped QK (mfma(K,Q) -> S^T): q = lane&31, kv in regs -> exp2 + row-sum
// lane-local. P->bf16 A-frags via pk2 + permlane32_swap (swap(t0,t2)->(w0,w2),
// swap(t1,t3)->(w1,w3)); PV = mfma(P, V). ZERO LDS in the kv loop (r6 spent
// 64 ds_write_b16 + 8 ds_read + 2 lgkmcnt(0) serializations per tile).
// REGISTER BUDGET (r4/r5/r7 lessons): launch_bounds 2nd arg caps the UNIFIED
// VGPR+AGPR pool; (256,4)/(256,3) spill catastrophically; r7's extra 96-reg
// K/V double-buffer spilled even at (256,2). Live set here ~200. Keep (256,2).
__global__ __launch_bounds__(256, 2) void k_attn(const bf16* __restrict__ Q,
                                                 const bf16* __restrict__ K,
                                                 const bf16* __restrict__ VT,
                                                 bf16* __restrict__ O) {
  __shared__ __align__(16) char smem[25344];  // merge: 3 waves x 64 x 33 f32
  int bid = blockIdx.x;
  int q32 = bid & 63;
  int hp = (bid >> 6) & 7;  // head pair
  int b = bid >> 9;
  int wv = threadIdx.x >> 6, lane = threadIdx.x & 63;
  int l31 = lane & 31, hi = lane >> 5;
  int q0 = q32 * 32;

  // Q B-frags: lane holds Q[q=q0+l31][d = f*16 + hi*8 + j]
  const bf16* qrow = Q + ((size_t)(b * SEQ + q0 + l31) * NDIM + hp * 128 + hi * 8);
  bf16x8 aq[2][4];
#pragma unroll
  for (int h = 0; h < 2; h++)
#pragma unroll
    for (int f = 0; f < 4; f++)
      aq[h][f] = *(const bf16x8*)(qrow + h * 64 + f * 16);

  const bf16* kb_ = K + ((size_t)(b * SEQ) * HD + hi * 8);
  const bf16* vrow = VT + ((size_t)(b * HD + l31) * SEQ + hi * 8);

  f32x16 acc[2][2] = {};  // [head][d-col-block]; lane: O[q=(r&3)+8(r>>2)+4hi][d=dc*32+l31]
  float lsum[2] = {0.f, 0.f};

  const int kvbeg = wv * (SEQ / 4);
  for (int kv0 = kvbeg; kv0 < kvbeg + SEQ / 4; kv0 += 64) {
    // K A-frags: lane holds K[kv = kv0+kvb*32+l31][d = f*16+hi*8+j]
    bf16x8 kf[2][4];
#pragma unroll
    for (int kvb = 0; kvb < 2; kvb++)
#pragma unroll
      for (int f = 0; f < 4; f++)
        kf[kvb][f] =
            *(const bf16x8*)(kb_ + (size_t)(kv0 + kvb * 32 + l31) * HD + f * 16);
    // V B-frags: lane holds V[kv = kv0+m*16+hi*8+j][d = dc*32+l31]
    bf16x8 vfr[4][2];
#pragma unroll
    for (int m = 0; m < 4; m++)
#pragma unroll
      for (int dc = 0; dc < 2; dc++)
        vfr[m][dc] = *(const bf16x8*)(vrow + (size_t)(dc * 32) * SEQ + kv0 + m * 16);

#pragma unroll
    for (int h = 0; h < 2; h++) {
#pragma unroll
      for (int kvb = 0; kvb < 2; kvb++) {
        // S^T = K . Q^T : lane q=l31, kv_local = (r&3)+8*(r>>2)+4*hi
        f32x16 s = {};
#pragma unroll
        for (int f = 0; f < 4; f++)
          s = __builtin_amdgcn_mfma_f32_32x32x16_bf16(kf[kvb][f], aq[h][f], s, 0, 0, 0);
        float p[16];
#pragma unroll
        for (int i = 0; i < 16; i++) {
          p[i] = __builtin_amdgcn_exp2f(s[i]);
          lsum[h] += p[i];
        }
        // redistribute to PV A-frag: P[q=l31][k = hi*8+j] per 16-kv group n
#pragma unroll
        for (int n = 0; n < 2; n++) {
          uint32_t t0 = pk2(p[8 * n + 0], p[8 * n + 1]);
          uint32_t t1 = pk2(p[8 * n + 2], p[8 * n + 3]);
          uint32_t t2 = pk2(p[8 * n + 4], p[8 * n + 5]);
          uint32_t t3 = pk2(p[8 * n + 6], p[8 * n + 7]);
          u32x2 rA = __builtin_amdgcn_permlane32_swap(t0, t2, false, false);
          u32x2 rB = __builtin_amdgcn_permlane32_swap(t1, t3, false, false);
          union { uint32_t u[4]; bf16x8 v; } af;
          af.u[0] = rA[0]; af.u[1] = rB[0]; af.u[2] = rA[1]; af.u[3] = rB[1];
#pragma unroll
          for (int dc = 0; dc < 2; dc++)
            acc[h][dc] = __builtin_amdgcn_mfma_f32_32x32x16_bf16(
                af.v, vfr[kvb * 2 + n][dc], acc[h][dc], 0, 0, 0);
        }
      }
    }
  }

  // combine the two hi-halves of each q's row sum (lane-local otherwise)
#pragma unroll
  for (int h = 0; h < 2; h++) lsum[h] += __shfl_xor(lsum[h], 32, 64);

  // merge kv-quarter partials through LDS, one head per half-round
  float* mb = (float*)smem;
  __syncthreads();
#pragma unroll
  for (int h = 0; h < 2; h++) {
    if (wv > 0) {
      float* dst = mb + ((size_t)(wv - 1) * 64 + lane) * 33;
#pragma unroll
      for (int dc = 0; dc < 2; dc++)
#pragma unroll
        for (int r = 0; r < 16; r++) dst[dc * 16 + r] = acc[h][dc][r];
      dst[32] = lsum[h];
    }
    __syncthreads();
    if (wv == 0) {
#pragma unroll
      for (int w = 0; w < 3; w++) {
        const float* src = mb + ((size_t)w * 64 + lane) * 33;
#pragma unroll
        for (int dc = 0; dc < 2; dc++)
#pragma unroll
          for (int r = 0; r < 16; r++) acc[h][dc][r] += src[dc * 16 + r];
        lsum[h] += src[32];
      }
    }
    __syncthreads();
  }

  if (wv == 0) {
#pragma unroll
    for (int h = 0; h < 2; h++) {
#pragma unroll
      for (int r = 0; r < 16; r++) {
        int q_r = (r & 3) + 8 * (r >> 2) + 4 * hi;
        float ls = __shfl(lsum[h], q_r, 64);
        float rinv = 1.0f / ls;
#pragma unroll
        for (int dc = 0; dc < 2; dc++)
          O[(size_t)(b * SEQ + q0 + q_r) * NDIM + (hp * 2 + h) * HD + dc * 32 +
            l31] = (bf16)(acc[h][dc][r] * rinv);
      }
    }
  }
}

extern "C" void kernel_launch(void* const* d_in, const int* in_sizes, int n_in,
                              void* d_out, int out_size, void* d_ws, size_t ws_size,
                              hipStream_t stream) {
  const float* x = (const float*)d_in[0];
  const float* Wq = (const float*)d_in[1];
  const float* Wk = (const float*)d_in[2];
  const float* Wv = (const float*)d_in[3];
  const float* Wp = (const float*)d_in[4];
  const float* bp = (const float*)d_in[5];
  float* out = (float*)d_out;

  size_t off = 0;
  char* wsb = (char*)d_ws;
  auto alloc = [&](size_t bytes) {
    char* p = wsb + off;
    off += bytes;
    return p;
  };
  bf16* x_bf = (bf16*)alloc((size_t)4096 * 1024 * 2);
  bf16* wqkvT = (bf16*)alloc((size_t)1152 * 1024 * 2);  // [WqT;WkT;WvT]
  bf16* wpT = (bf16*)alloc((size_t)1024 * 1024 * 2);
  bf16* Qb = (bf16*)alloc((size_t)4096 * 1024 * 2);
  bf16* Kb = (bf16*)alloc((size_t)4096 * 64 * 2);
  bf16* VTb = (bf16*)alloc((size_t)2 * 64 * 2048 * 2);
  bf16* AOb = (bf16*)alloc((size_t)4096 * 1024 * 2);

  k_cvt<<<4096, 256, 0, stream>>>(x, x_bf, 4096 * 1024);
  k_transpose<<<dim3(32, 32), 256, 0, stream>>>(Wq, wqkvT, 1024, 1024);
  k_transpose<<<dim3(2, 32), 256, 0, stream>>>(Wk, wqkvT + (size_t)1024 * 1024,
                                               1024, 64);
  k_transpose<<<dim3(2, 32), 256, 0, stream>>>(Wv, wqkvT + (size_t)1088 * 1024,
                                               1024, 64);
  k_transpose<<<dim3(32, 32), 256, 0, stream>>>(Wp, wpT, 1024, 1024);

  // fused Q/K/V projection: N = 1152 = 1024(Q) + 64(K) + 64(V)
  k_gemm<128, 128, 64, 64, 3><<<dim3(9, 32), 256, 0, stream>>>(
      x_bf, wqkvT, Qb, Kb, VTb, nullptr, 4096, 1152, 1024, QSCALE);

  k_attn<<<1024, 256, 0, stream>>>(Qb, Kb, VTb, AOb);

  // output projection + bias, fp32 out
  k_gemm<128, 128, 64, 64, 2><<<dim3(8, 32), 256, 0, stream>>>(
      AOb, wpT, out, nullptr, nullptr, bp, 4096, 1024, 1024, 1.0f);
}

// Round 9
// 117.018 us; speedup vs baseline: 1.7390x; 1.1595x over previous
//
#include <hip/hip_runtime.h>
#include <hip/hip_bf16.h>
#include <stdint.h>

using bf16 = __bf16;
using bf16x4 = __attribute__((ext_vector_type(4))) __bf16;
using bf16x8 = __attribute__((ext_vector_type(8))) __bf16;
using f32x4 = __attribute__((ext_vector_type(4))) float;
using f32x16 = __attribute__((ext_vector_type(16))) float;
using u32x2 = __attribute__((ext_vector_type(2))) unsigned int;

static constexpr int SEQ = 2048;
static constexpr int NDIM = 1024;
static constexpr int NHEAD = 16;
static constexpr int HD = 64;
// fold softmax scale and log2(e) into Q so scores are already in log2 domain
static constexpr float QSCALE = 0.125f * 1.4426950408889634f;

__device__ __forceinline__ void load_lds16(const void* g, void* l) {
  __builtin_amdgcn_global_load_lds(
      (const __attribute__((address_space(1))) void*)g,
      (__attribute__((address_space(3))) void*)l, 16, 0, 0);
}

// pack two fp32 -> one u32 of two bf16 (lo = a, hi = b)
__device__ __forceinline__ uint32_t pk2(float a, float b) {
  uint16_t ua = __builtin_bit_cast(uint16_t, (bf16)a);
  uint16_t ub = __builtin_bit_cast(uint16_t, (bf16)b);
  return (uint32_t)ua | ((uint32_t)ub << 16);
}

// ---------------- fp32 -> bf16 convert (4 elems/thread) ----------------
__global__ __launch_bounds__(256) void k_cvt(const float* __restrict__ in,
                                             bf16* __restrict__ out, int n) {
  int i = (blockIdx.x * 256 + threadIdx.x) * 4;
  if (i >= n) return;
  float4 v = *(const float4*)(in + i);
  bf16x4 o;
  o[0] = (bf16)v.x; o[1] = (bf16)v.y; o[2] = (bf16)v.z; o[3] = (bf16)v.w;
  *(bf16x4*)(out + i) = o;
}

// ---------------- W (K x N) fp32 -> WT (N x K) bf16 ----------------
__global__ __launch_bounds__(256) void k_transpose(const float* __restrict__ W,
                                                   bf16* __restrict__ WT,
                                                   int K, int N) {
  __shared__ float t[32][33];
  int n0 = blockIdx.x * 32, k0 = blockIdx.y * 32;
  int tx = threadIdx.x & 31, ty = threadIdx.x >> 5;  // 32 x 8
#pragma unroll
  for (int i = 0; i < 4; i++)
    t[ty + 8 * i][tx] = W[(size_t)(k0 + ty + 8 * i) * N + n0 + tx];
  __syncthreads();
#pragma unroll
  for (int i = 0; i < 4; i++)
    WT[(size_t)(n0 + ty + 8 * i) * K + k0 + tx] = (bf16)t[tx][ty + 8 * i];
}

// ---------------- bf16 GEMM: C = A(MxK) @ BT(NxK)^T ----------------
// MODE 2: C fp32 + bias                           (output projection)
// MODE 3: fused QKV: col<1024 -> Q bf16 * scale; col in [1024,1088) -> K bf16
//         (C2); col >= 1088 -> V bf16 stored transposed per batch (C3)
template <int BM, int BN, int WM, int WN, int MODE>
__global__ __launch_bounds__(256) void k_gemm(const bf16* __restrict__ A,
                                              const bf16* __restrict__ BT,
                                              void* __restrict__ C,
                                              void* __restrict__ C2,
                                              void* __restrict__ C3,
                                              const float* __restrict__ bias,
                                              int M, int N, int K, float scale) {
  __shared__ __align__(16) char As[BM * 128];
  __shared__ __align__(16) char Bs[BN * 128];
  const int lane = threadIdx.x & 63;
  const int wv = threadIdx.x >> 6;
  constexpr int NWC = BN / WN;
  const int wr = wv / NWC, wc = wv % NWC;
  const int g = lane >> 4, l15 = lane & 15;
  const int m0 = blockIdx.y * BM, n0 = blockIdx.x * BN;
  constexpr int MI = WM / 16, NI = WN / 16;

  f32x4 acc[MI][NI] = {};

  const int srow = lane >> 3;   // staging row within 8-row chunk
  const int c16 = lane & 7;     // staging 16B-column within row

  for (int kt = 0; kt < K; kt += 64) {
    // stage A tile (BM x 64 bf16), XOR-swizzled source, linear LDS dest
#pragma unroll
    for (int j = wv; j < BM / 8; j += 4) {
      int row = j * 8 + srow;
      const char* src = (const char*)A + (size_t)(m0 + row) * (K * 2) + kt * 2 +
                        ((c16 ^ (row & 7)) << 4);
      load_lds16(src, As + j * 1024);
    }
#pragma unroll
    for (int j = wv; j < BN / 8; j += 4) {
      int row = j * 8 + srow;
      const char* src = (const char*)BT + (size_t)(n0 + row) * (K * 2) + kt * 2 +
                        ((c16 ^ (row & 7)) << 4);
      load_lds16(src, Bs + j * 1024);
    }
    __syncthreads();
#pragma unroll
    for (int kk = 0; kk < 2; kk++) {
      bf16x8 af[MI], bfr[NI];
#pragma unroll
      for (int mi = 0; mi < MI; mi++) {
        int row = wr * WM + mi * 16 + l15;
        af[mi] = *(const bf16x8*)(As + row * 128 + (((kk * 4 + g) ^ (row & 7)) << 4));
      }
#pragma unroll
      for (int ni = 0; ni < NI; ni++) {
        int row = wc * WN + ni * 16 + l15;
        bfr[ni] = *(const bf16x8*)(Bs + row * 128 + (((kk * 4 + g) ^ (row & 7)) << 4));
      }
#pragma unroll
      for (int mi = 0; mi < MI; mi++)
#pragma unroll
        for (int ni = 0; ni < NI; ni++)
          acc[mi][ni] = __builtin_amdgcn_mfma_f32_16x16x32_bf16(af[mi], bfr[ni],
                                                                acc[mi][ni], 0, 0, 0);
    }
    __syncthreads();
  }

#pragma unroll
  for (int mi = 0; mi < MI; mi++)
#pragma unroll
    for (int ni = 0; ni < NI; ni++) {
      int col = n0 + wc * WN + ni * 16 + l15;
      int rowb = m0 + wr * WM + mi * 16 + g * 4;
      if (MODE == 2) {
        float bv = bias[col];
#pragma unroll
        for (int r = 0; r < 4; r++)
          ((float*)C)[(size_t)(rowb + r) * N + col] = acc[mi][ni][r] + bv;
      } else {  // MODE 3: fused QKV epilogue
        if (col < 1024) {
#pragma unroll
          for (int r = 0; r < 4; r++)
            ((bf16*)C)[(size_t)(rowb + r) * 1024 + col] =
                (bf16)(acc[mi][ni][r] * scale);
        } else if (col < 1088) {
#pragma unroll
          for (int r = 0; r < 4; r++)
            ((bf16*)C2)[(size_t)(rowb + r) * 64 + (col - 1024)] =
                (bf16)acc[mi][ni][r];
        } else {
#pragma unroll
          for (int r = 0; r < 4; r++) {
            int m = rowb + r;
            ((bf16*)C3)[((size_t)((m >> 11) * 64 + (col - 1088))) * 2048 +
                        (m & 2047)] = (bf16)acc[mi][ni][r];
          }
        }
      }
    }
}

// ---- fused attention: LDS-staged K/V (coalesced) + in-register softmax -----
// Q: (B*SEQ,1024) bf16 pre-scaled; K: (B*SEQ,64) bf16; VT: (B,64,SEQ) bf16.
// grid = B * H * (SEQ/64) = 1024 blocks; block = 4 waves = 2 qsub x 2 kvhalf.
// Each wave: 32 q-rows, 1 head, over its kv-half (16 tiles of 64).
// The qs-pair at the same kv-half SHARES K/V tiles staged in LDS via
// global_load_lds (contiguous 16B/lane -> 100% L2 sector utilization; r8's
// register-direct fragment loads used only 32B of each 64B line -> 2x waste).
// XOR swizzle identical to k_gemm (pre-swizzled source, swizzled ds_read);
// fragment reads hit all 32 banks uniformly (8 lanes/16B-slot, distinct rows).
// Swapped QK (mfma(K,Q) -> S^T): softmax lane-local; pk2+permlane32_swap
// builds PV A-frags in-register (r8, verified).
// REGISTER BUDGET: 1 head/wave => acc 32 AGPR + aq 16 + kf 16 + p 16 + temps
// ~ 105 unified < 128, so (256,4) is SAFE here (r4 spilled because its live
// set was ~164; tripwire = WRITE_SIZE >> 8.2 MB).
__global__ __launch_bounds__(256, 4) void k_attn(const bf16* __restrict__ Q,
                                                 const bf16* __restrict__ K,
                                                 const bf16* __restrict__ VT,
                                                 bf16* __restrict__ O) {
  // [kh][Ktile 8KB] at 0..16K, [kh][Vtile 8KB] at 16K..32K; merge reuses.
  __shared__ __align__(16) char smem[32768];
  int bid = blockIdx.x;
  int q64 = bid & 31;
  int h = (bid >> 5) & 15;
  int b = bid >> 9;
  int wv = threadIdx.x >> 6, lane = threadIdx.x & 63;
  int l31 = lane & 31, hi = lane >> 5;
  int qs = wv & 1, kh = wv >> 1;
  int q0 = q64 * 64 + qs * 32;

  // Q B-frags: lane holds Q[q=q0+l31][d = f*16 + hi*8 + j]
  const bf16* qrow =
      Q + ((size_t)(b * SEQ + q0 + l31) * NDIM + h * HD + hi * 8);
  bf16x8 aq[4];
#pragma unroll
  for (int f = 0; f < 4; f++) aq[f] = *(const bf16x8*)(qrow + f * 16);

  char* Kl = smem + kh * 8192;          // K tile [64 kv][128B], swizzled
  char* Vl = smem + 16384 + kh * 8192;  // V tile [64 d][128B kv], swizzled
  const int srow = lane >> 3, c16 = lane & 7;

  f32x16 acc[2] = {};  // [dc]; lane: O[q=(r&3)+8(r>>2)+4hi][d=dc*32+l31]
  float lsum = 0.f;

  const int kvbeg = kh * (SEQ / 2);
#pragma unroll 1
  for (int t = 0; t < 16; t++) {
    const int kv0 = kvbeg + t * 64;
    // ---- stage: qs=0 loads K tile, qs=1 loads V tile (coalesced, swizzled src)
    if (qs == 0) {
#pragma unroll
      for (int j = 0; j < 8; j++) {
        const char* src = (const char*)K +
                          (size_t)(b * SEQ + kv0 + j * 8 + srow) * 128 +
                          ((c16 ^ srow) << 4);
        load_lds16(src, Kl + j * 1024);
      }
    } else {
#pragma unroll
      for (int j = 0; j < 8; j++) {
        const char* src = (const char*)VT +
                          (size_t)(b * 64 + j * 8 + srow) * (SEQ * 2) +
                          (size_t)kv0 * 2 + ((c16 ^ srow) << 4);
        load_lds16(src, Vl + j * 1024);
      }
    }
    __syncthreads();
    // ---- compute on staged tile
#pragma unroll
    for (int kvb = 0; kvb < 2; kvb++) {
      bf16x8 kf[4];
#pragma unroll
      for (int f = 0; f < 4; f++)
        kf[f] = *(const bf16x8*)(Kl + (kvb * 32 + l31) * 128 +
                                 (((f * 2 + hi) ^ (l31 & 7)) << 4));
      f32x16 s = {};
#pragma unroll
      for (int f = 0; f < 4; f++)
        s = __builtin_amdgcn_mfma_f32_32x32x16_bf16(kf[f], aq[f], s, 0, 0, 0);
      float p[16];
#pragma unroll
      for (int i = 0; i < 16; i++) {
        p[i] = __builtin_amdgcn_exp2f(s[i]);
        lsum += p[i];
      }
#pragma unroll
      for (int n = 0; n < 2; n++) {
        uint32_t t0 = pk2(p[8 * n + 0], p[8 * n + 1]);
        uint32_t t1 = pk2(p[8 * n + 2], p[8 * n + 3]);
        uint32_t t2 = pk2(p[8 * n + 4], p[8 * n + 5]);
        uint32_t t3 = pk2(p[8 * n + 6], p[8 * n + 7]);
        u32x2 rA = __builtin_amdgcn_permlane32_swap(t0, t2, false, false);
        u32x2 rB = __builtin_amdgcn_permlane32_swap(t1, t3, false, false);
        union { uint32_t u[4]; bf16x8 v; } af;
        af.u[0] = rA[0]; af.u[1] = rB[0]; af.u[2] = rA[1]; af.u[3] = rB[1];
#pragma unroll
        for (int dc = 0; dc < 2; dc++) {
          bf16x8 vf = *(const bf16x8*)(Vl + (dc * 32 + l31) * 128 +
                                       (((kvb * 4 + n * 2 + hi) ^ (l31 & 7))
                                        << 4));
          acc[dc] = __builtin_amdgcn_mfma_f32_32x32x16_bf16(af.v, vf, acc[dc],
                                                            0, 0, 0);
        }
      }
    }
    __syncthreads();
  }

  // combine the two hi-halves of each q's row sum (lane-local otherwise)
  lsum += __shfl_xor(lsum, 32, 64);

  // merge the two kv-halves: kh=1 writes partials, kh=0 adds + outputs.
  float* mb = (float*)smem;  // [2 qs][64 lanes][33 f32] = 16896 B
  __syncthreads();
  if (kh == 1) {
    float* dst = mb + ((size_t)(qs * 64 + lane)) * 33;
#pragma unroll
    for (int dc = 0; dc < 2; dc++)
#pragma unroll
      for (int r = 0; r < 16; r++) dst[dc * 16 + r] = acc[dc][r];
    dst[32] = lsum;
  }
  __syncthreads();
  if (kh == 0) {
    const float* src = mb + ((size_t)(qs * 64 + lane)) * 33;
#pragma unroll
    for (int dc = 0; dc < 2; dc++)
#pragma unroll
      for (int r = 0; r < 16; r++) acc[dc][r] += src[dc * 16 + r];
    lsum += src[32];
#pragma unroll
    for (int r = 0; r < 16; r++) {
      int q_r = (r & 3) + 8 * (r >> 2) + 4 * hi;
      float ls = __shfl(lsum, q_r, 64);
      float rinv = 1.0f / ls;
#pragma unroll
      for (int dc = 0; dc < 2; dc++)
        O[(size_t)(b * SEQ + q0 + q_r) * NDIM + h * HD + dc * 32 + l31] =
            (bf16)(acc[dc][r] * rinv);
    }
  }
}

extern "C" void kernel_launch(void* const* d_in, const int* in_sizes, int n_in,
                              void* d_out, int out_size, void* d_ws, size_t ws_size,
                              hipStream_t stream) {
  const float* x = (const float*)d_in[0];
  const float* Wq = (const float*)d_in[1];
  const float* Wk = (const float*)d_in[2];
  const float* Wv = (const float*)d_in[3];
  const float* Wp = (const float*)d_in[4];
  const float* bp = (const float*)d_in[5];
  float* out = (float*)d_out;

  size_t off = 0;
  char* wsb = (char*)d_ws;
  auto alloc = [&](size_t bytes) {
    char* p = wsb + off;
    off += bytes;
    return p;
  };
  bf16* x_bf = (bf16*)alloc((size_t)4096 * 1024 * 2);
  bf16* wqkvT = (bf16*)alloc((size_t)1152 * 1024 * 2);  // [WqT;WkT;WvT]
  bf16* wpT = (bf16*)alloc((size_t)1024 * 1024 * 2);
  bf16* Qb = (bf16*)alloc((size_t)4096 * 1024 * 2);
  bf16* Kb = (bf16*)alloc((size_t)4096 * 64 * 2);
  bf16* VTb = (bf16*)alloc((size_t)2 * 64 * 2048 * 2);
  bf16* AOb = (bf16*)alloc((size_t)4096 * 1024 * 2);

  k_cvt<<<4096, 256, 0, stream>>>(x, x_bf, 4096 * 1024);
  k_transpose<<<dim3(32, 32), 256, 0, stream>>>(Wq, wqkvT, 1024, 1024);
  k_transpose<<<dim3(2, 32), 256, 0, stream>>>(Wk, wqkvT + (size_t)1024 * 1024,
                                               1024, 64);
  k_transpose<<<dim3(2, 32), 256, 0, stream>>>(Wv, wqkvT + (size_t)1088 * 1024,
                                               1024, 64);
  k_transpose<<<dim3(32, 32), 256, 0, stream>>>(Wp, wpT, 1024, 1024);

  // fused Q/K/V projection: N = 1152 = 1024(Q) + 64(K) + 64(V)
  k_gemm<128, 128, 64, 64, 3><<<dim3(9, 32), 256, 0, stream>>>(
      x_bf, wqkvT, Qb, Kb, VTb, nullptr, 4096, 1152, 1024, QSCALE);

  k_attn<<<1024, 256, 0, stream>>>(Qb, Kb, VTb, AOb);

  // output projection + bias, fp32 out
  k_gemm<128, 128, 64, 64, 2><<<dim3(8, 32), 256, 0, stream>>>(
      AOb, wpT, out, nullptr, nullptr, bp, 4096, 1024, 1024, 1.0f);
}

// Round 10
// 111.832 us; speedup vs baseline: 1.8196x; 1.0464x over previous
//
#include <hip/hip_runtime.h>
#include <hip/hip_bf16.h>
#include <stdint.h>

using bf16 = __bf16;
using bf16x4 = __attribute__((ext_vector_type(4))) __bf16;
using bf16x8 = __attribute__((ext_vector_type(8))) __bf16;
using f32x4 = __attribute__((ext_vector_type(4))) float;
using f32x16 = __attribute__((ext_vector_type(16))) float;
using u32x2 = __attribute__((ext_vector_type(2))) unsigned int;

static constexpr int SEQ = 2048;
static constexpr int NDIM = 1024;
static constexpr int NHEAD = 16;
static constexpr int HD = 64;
// fold softmax scale and log2(e) into Q so scores are already in log2 domain
static constexpr float QSCALE = 0.125f * 1.4426950408889634f;

__device__ __forceinline__ void load_lds16(const void* g, void* l) {
  __builtin_amdgcn_global_load_lds(
      (const __attribute__((address_space(1))) void*)g,
      (__attribute__((address_space(3))) void*)l, 16, 0, 0);
}

// pack two fp32 -> one u32 of two bf16 (lo = a, hi = b)
__device__ __forceinline__ uint32_t pk2(float a, float b) {
  uint16_t ua = __builtin_bit_cast(uint16_t, (bf16)a);
  uint16_t ub = __builtin_bit_cast(uint16_t, (bf16)b);
  return (uint32_t)ua | ((uint32_t)ub << 16);
}

// ---------------- fp32 -> bf16 convert (4 elems/thread) ----------------
__global__ __launch_bounds__(256) void k_cvt(const float* __restrict__ in,
                                             bf16* __restrict__ out, int n) {
  int i = (blockIdx.x * 256 + threadIdx.x) * 4;
  if (i >= n) return;
  float4 v = *(const float4*)(in + i);
  bf16x4 o;
  o[0] = (bf16)v.x; o[1] = (bf16)v.y; o[2] = (bf16)v.z; o[3] = (bf16)v.w;
  *(bf16x4*)(out + i) = o;
}

// ---------------- W (K x N) fp32 -> WT (N x K) bf16 ----------------
__global__ __launch_bounds__(256) void k_transpose(const float* __restrict__ W,
                                                   bf16* __restrict__ WT,
                                                   int K, int N) {
  __shared__ float t[32][33];
  int n0 = blockIdx.x * 32, k0 = blockIdx.y * 32;
  int tx = threadIdx.x & 31, ty = threadIdx.x >> 5;  // 32 x 8
#pragma unroll
  for (int i = 0; i < 4; i++)
    t[ty + 8 * i][tx] = W[(size_t)(k0 + ty + 8 * i) * N + n0 + tx];
  __syncthreads();
#pragma unroll
  for (int i = 0; i < 4; i++)
    WT[(size_t)(n0 + ty + 8 * i) * K + k0 + tx] = (bf16)t[tx][ty + 8 * i];
}

// ---------------- bf16 GEMM: C = A(MxK) @ BT(NxK)^T ----------------
// MODE 2: C fp32 + bias                           (output projection)
// MODE 3: fused QKV: col<1024 -> Q bf16 * scale; col in [1024,1088) -> K bf16
//         (C2); col >= 1088 -> V bf16 stored transposed per batch (C3)
template <int BM, int BN, int WM, int WN, int MODE>
__global__ __launch_bounds__(256) void k_gemm(const bf16* __restrict__ A,
                                              const bf16* __restrict__ BT,
                                              void* __restrict__ C,
                                              void* __restrict__ C2,
                                              void* __restrict__ C3,
                                              const float* __restrict__ bias,
                                              int M, int N, int K, float scale) {
  __shared__ __align__(16) char As[BM * 128];
  __shared__ __align__(16) char Bs[BN * 128];
  const int lane = threadIdx.x & 63;
  const int wv = threadIdx.x >> 6;
  constexpr int NWC = BN / WN;
  const int wr = wv / NWC, wc = wv % NWC;
  const int g = lane >> 4, l15 = lane & 15;
  const int m0 = blockIdx.y * BM, n0 = blockIdx.x * BN;
  constexpr int MI = WM / 16, NI = WN / 16;

  f32x4 acc[MI][NI] = {};

  const int srow = lane >> 3;   // staging row within 8-row chunk
  const int c16 = lane & 7;     // staging 16B-column within row

  for (int kt = 0; kt < K; kt += 64) {
    // stage A tile (BM x 64 bf16), XOR-swizzled source, linear LDS dest
#pragma unroll
    for (int j = wv; j < BM / 8; j += 4) {
      int row = j * 8 + srow;
      const char* src = (const char*)A + (size_t)(m0 + row) * (K * 2) + kt * 2 +
                        ((c16 ^ (row & 7)) << 4);
      load_lds16(src, As + j * 1024);
    }
#pragma unroll
    for (int j = wv; j < BN / 8; j += 4) {
      int row = j * 8 + srow;
      const char* src = (const char*)BT + (size_t)(n0 + row) * (K * 2) + kt * 2 +
                        ((c16 ^ (row & 7)) << 4);
      load_lds16(src, Bs + j * 1024);
    }
    __syncthreads();
#pragma unroll
    for (int kk = 0; kk < 2; kk++) {
      bf16x8 af[MI], bfr[NI];
#pragma unroll
      for (int mi = 0; mi < MI; mi++) {
        int row = wr * WM + mi * 16 + l15;
        af[mi] = *(const bf16x8*)(As + row * 128 + (((kk * 4 + g) ^ (row & 7)) << 4));
      }
#pragma unroll
      for (int ni = 0; ni < NI; ni++) {
        int row = wc * WN + ni * 16 + l15;
        bfr[ni] = *(const bf16x8*)(Bs + row * 128 + (((kk * 4 + g) ^ (row & 7)) << 4));
      }
#pragma unroll
      for (int mi = 0; mi < MI; mi++)
#pragma unroll
        for (int ni = 0; ni < NI; ni++)
          acc[mi][ni] = __builtin_amdgcn_mfma_f32_16x16x32_bf16(af[mi], bfr[ni],
                                                                acc[mi][ni], 0, 0, 0);
    }
    __syncthreads();
  }

#pragma unroll
  for (int mi = 0; mi < MI; mi++)
#pragma unroll
    for (int ni = 0; ni < NI; ni++) {
      int col = n0 + wc * WN + ni * 16 + l15;
      int rowb = m0 + wr * WM + mi * 16 + g * 4;
      if (MODE == 2) {
        float bv = bias[col];
#pragma unroll
        for (int r = 0; r < 4; r++)
          ((float*)C)[(size_t)(rowb + r) * N + col] = acc[mi][ni][r] + bv;
      } else {  // MODE 3: fused QKV epilogue
        if (col < 1024) {
#pragma unroll
          for (int r = 0; r < 4; r++)
            ((bf16*)C)[(size_t)(rowb + r) * 1024 + col] =
                (bf16)(acc[mi][ni][r] * scale);
        } else if (col < 1088) {
#pragma unroll
          for (int r = 0; r < 4; r++)
            ((bf16*)C2)[(size_t)(rowb + r) * 64 + (col - 1024)] =
                (bf16)acc[mi][ni][r];
        } else {
#pragma unroll
          for (int r = 0; r < 4; r++) {
            int m = rowb + r;
            ((bf16*)C3)[((size_t)((m >> 11) * 64 + (col - 1088))) * 2048 +
                        (m & 2047)] = (bf16)acc[mi][ni][r];
          }
        }
      }
    }
}

// ---- fused attention: 8-wave blocks, shared LDS K/V tiles, 2-phase dbuf ----
// Q: (B*SEQ,1024) bf16 pre-scaled; K: (B*SEQ,64) bf16; VT: (B,64,SEQ) bf16.
// grid = B * H * (SEQ/128) = 512 blocks; block = 8 waves = 4 qsub x 2 kvhalf.
// Each wave: 32 q-rows, 1 head, over its kv-half; the FOUR q-waves of a
// kv-half share one staged K/V tile pair (16 KB), each staging 4 KB.
// 2-phase pipeline (T3 minimum): STAGE(buf^1, t+1) issued BEFORE compute(buf);
// the single __syncthreads per tile drains vmcnt AFTER a full compute phase,
// so L2 latency hides under QK/exp2/PV (r9 exposed it every tile).
// Swapped QK (mfma(K,Q) -> S^T): softmax lane-local; pk2+permlane32_swap
// builds PV A-frags in-register (r8, verified).
// REGISTER BUDGET (r4/r5/r7 lessons): (512,4) caps the unified pool at 128 --
// same cap r9 compiled cleanly under (60 arch, no spill); live set unchanged.
// Tripwire = WRITE_SIZE >> 8.2 MB means spill: revert.
__global__ __launch_bounds__(512, 4) void k_attn(const bf16* __restrict__ Q,
                                                 const bf16* __restrict__ K,
                                                 const bf16* __restrict__ VT,
                                                 bf16* __restrict__ O) {
  // [buf 0/1][kh 0/1][K 8KB | V 8KB] = 64 KB; merge reuses after final barrier
  __shared__ __align__(16) char smem[65536];
  int bid = blockIdx.x;
  int q128 = bid & 15;
  int h = (bid >> 4) & 15;
  int b = bid >> 8;
  int wv = threadIdx.x >> 6, lane = threadIdx.x & 63;
  int l31 = lane & 31, hi = lane >> 5;
  int qs = wv & 3, kh = wv >> 2;
  int q0 = q128 * 128 + qs * 32;

  // Q B-frags: lane holds Q[q=q0+l31][d = f*16 + hi*8 + j]
  const bf16* qrow =
      Q + ((size_t)(b * SEQ + q0 + l31) * NDIM + h * HD + hi * 8);
  bf16x8 aq[4];
#pragma unroll
  for (int f = 0; f < 4; f++) aq[f] = *(const bf16x8*)(qrow + f * 16);

  const int srow = lane >> 3, c16 = lane & 7;
  const int kvbeg = kh * (SEQ / 2);

  // stage tile t (64 kv) into buffer bb: this wave stages chunks qs*4..qs*4+3
  // (chunk<8: K rows chunk*8.., chunk>=8: V rows (chunk-8)*8..); 1KB each.
  auto stage = [&](int bb, int t) {
    char* base = smem + bb * 32768 + kh * 16384;
    const int kv0 = kvbeg + t * 64;
#pragma unroll
    for (int j = 0; j < 4; j++) {
      int c = qs * 4 + j;
      if (c < 8) {
        const char* src = (const char*)K +
                          (size_t)(b * SEQ + kv0 + c * 8 + srow) * 128 +
                          ((c16 ^ srow) << 4);
        load_lds16(src, base + c * 1024);
      } else {
        const char* src = (const char*)VT +
                          (size_t)(b * 64 + (c - 8) * 8 + srow) * (SEQ * 2) +
                          (size_t)kv0 * 2 + ((c16 ^ srow) << 4);
        load_lds16(src, base + c * 1024);
      }
    }
  };

  f32x16 acc[2] = {};  // [dc]; lane: O[q=(r&3)+8(r>>2)+4hi][d=dc*32+l31]
  float lsum = 0.f;

  stage(0, 0);
  __syncthreads();

#pragma unroll 1
  for (int t = 0; t < 16; t++) {
    char* Kl = smem + (t & 1) * 32768 + kh * 16384;
    char* Vl = Kl + 8192;
    // prefetch next tile into the other buffer (safe: it was consumed at t-1)
    if (t < 15) stage((t & 1) ^ 1, t + 1);
    // ---- compute on staged tile
#pragma unroll
    for (int kvb = 0; kvb < 2; kvb++) {
      bf16x8 kf[4];
#pragma unroll
      for (int f = 0; f < 4; f++)
        kf[f] = *(const bf16x8*)(Kl + (kvb * 32 + l31) * 128 +
                                 (((f * 2 + hi) ^ (l31 & 7)) << 4));
      f32x16 s = {};
#pragma unroll
      for (int f = 0; f < 4; f++)
        s = __builtin_amdgcn_mfma_f32_32x32x16_bf16(kf[f], aq[f], s, 0, 0, 0);
      float p[16];
#pragma unroll
      for (int i = 0; i < 16; i++) {
        p[i] = __builtin_amdgcn_exp2f(s[i]);
        lsum += p[i];
      }
#pragma unroll
      for (int n = 0; n < 2; n++) {
        uint32_t t0 = pk2(p[8 * n + 0], p[8 * n + 1]);
        uint32_t t1 = pk2(p[8 * n + 2], p[8 * n + 3]);
        uint32_t t2 = pk2(p[8 * n + 4], p[8 * n + 5]);
        uint32_t t3 = pk2(p[8 * n + 6], p[8 * n + 7]);
        u32x2 rA = __builtin_amdgcn_permlane32_swap(t0, t2, false, false);
        u32x2 rB = __builtin_amdgcn_permlane32_swap(t1, t3, false, false);
        union { uint32_t u[4]; bf16x8 v; } af;
        af.u[0] = rA[0]; af.u[1] = rB[0]; af.u[2] = rA[1]; af.u[3] = rB[1];
#pragma unroll
        for (int dc = 0; dc < 2; dc++) {
          bf16x8 vf = *(const bf16x8*)(Vl + (dc * 32 + l31) * 128 +
                                       (((kvb * 4 + n * 2 + hi) ^ (l31 & 7))
                                        << 4));
          acc[dc] = __builtin_amdgcn_mfma_f32_32x32x16_bf16(af.v, vf, acc[dc],
                                                            0, 0, 0);
        }
      }
    }
    __syncthreads();  // drains prefetch vmcnt; next iter flips buffers
  }

  // combine the two hi-halves of each q's row sum (lane-local otherwise)
  lsum += __shfl_xor(lsum, 32, 64);

  // merge the two kv-halves: kh=1 writes partials, kh=0 adds + outputs.
  float* mb = (float*)smem;  // [4 qs][64 lanes][33 f32] = 33792 B
  if (kh == 1) {
    float* dst = mb + ((size_t)(qs * 64 + lane)) * 33;
#pragma unroll
    for (int dc = 0; dc < 2; dc++)
#pragma unroll
      for (int r = 0; r < 16; r++) dst[dc * 16 + r] = acc[dc][r];
    dst[32] = lsum;
  }
  __syncthreads();
  if (kh == 0) {
    const float* src = mb + ((size_t)(qs * 64 + lane)) * 33;
#pragma unroll
    for (int dc = 0; dc < 2; dc++)
#pragma unroll
      for (int r = 0; r < 16; r++) acc[dc][r] += src[dc * 16 + r];
    lsum += src[32];
#pragma unroll
    for (int r = 0; r < 16; r++) {
      int q_r = (r & 3) + 8 * (r >> 2) + 4 * hi;
      float ls = __shfl(lsum, q_r, 64);
      float rinv = 1.0f / ls;
#pragma unroll
      for (int dc = 0; dc < 2; dc++)
        O[(size_t)(b * SEQ + q0 + q_r) * NDIM + h * HD + dc * 32 + l31] =
            (bf16)(acc[dc][r] * rinv);
    }
  }
}

extern "C" void kernel_launch(void* const* d_in, const int* in_sizes, int n_in,
                              void* d_out, int out_size, void* d_ws, size_t ws_size,
                              hipStream_t stream) {
  const float* x = (const float*)d_in[0];
  const float* Wq = (const float*)d_in[1];
  const float* Wk = (const float*)d_in[2];
  const float* Wv = (const float*)d_in[3];
  const float* Wp = (const float*)d_in[4];
  const float* bp = (const float*)d_in[5];
  float* out = (float*)d_out;

  size_t off = 0;
  char* wsb = (char*)d_ws;
  auto alloc = [&](size_t bytes) {
    char* p = wsb + off;
    off += bytes;
    return p;
  };
  bf16* x_bf = (bf16*)alloc((size_t)4096 * 1024 * 2);
  bf16* wqkvT = (bf16*)alloc((size_t)1152 * 1024 * 2);  // [WqT;WkT;WvT]
  bf16* wpT = (bf16*)alloc((size_t)1024 * 1024 * 2);
  bf16* Qb = (bf16*)alloc((size_t)4096 * 1024 * 2);
  bf16* Kb = (bf16*)alloc((size_t)4096 * 64 * 2);
  bf16* VTb = (bf16*)alloc((size_t)2 * 64 * 2048 * 2);
  bf16* AOb = (bf16*)alloc((size_t)4096 * 1024 * 2);

  k_cvt<<<4096, 256, 0, stream>>>(x, x_bf, 4096 * 1024);
  k_transpose<<<dim3(32, 32), 256, 0, stream>>>(Wq, wqkvT, 1024, 1024);
  k_transpose<<<dim3(2, 32), 256, 0, stream>>>(Wk, wqkvT + (size_t)1024 * 1024,
                                               1024, 64);
  k_transpose<<<dim3(2, 32), 256, 0, stream>>>(Wv, wqkvT + (size_t)1088 * 1024,
                                               1024, 64);
  k_transpose<<<dim3(32, 32), 256, 0, stream>>>(Wp, wpT, 1024, 1024);

  // fused Q/K/V projection: N = 1152 = 1024(Q) + 64(K) + 64(V)
  k_gemm<128, 128, 64, 64, 3><<<dim3(9, 32), 256, 0, stream>>>(
      x_bf, wqkvT, Qb, Kb, VTb, nullptr, 4096, 1152, 1024, QSCALE);

  k_attn<<<512, 512, 0, stream>>>(Qb, Kb, VTb, AOb);

  // output projection + bias, fp32 out
  k_gemm<128, 128, 64, 64, 2><<<dim3(8, 32), 256, 0, stream>>>(
      AOb, wpT, out, nullptr, nullptr, bp, 4096, 1024, 1024, 1.0f);
}

// Round 11
// 102.947 us; speedup vs baseline: 1.9767x; 1.0863x over previous
//
#include <hip/hip_runtime.h>
#include <hip/hip_bf16.h>
#include <stdint.h>

using bf16 = __bf16;
using bf16x4 = __attribute__((ext_vector_type(4))) __bf16;
using bf16x8 = __attribute__((ext_vector_type(8))) __bf16;
using f32x4 = __attribute__((ext_vector_type(4))) float;
using f32x16 = __attribute__((ext_vector_type(16))) float;
using u32x2 = __attribute__((ext_vector_type(2))) unsigned int;

static constexpr int SEQ = 2048;
static constexpr int NDIM = 1024;
static constexpr int NHEAD = 16;
static constexpr int HD = 64;
// fold softmax scale and log2(e) into Q so scores are already in log2 domain
static constexpr float QSCALE = 0.125f * 1.4426950408889634f;

__device__ __forceinline__ void load_lds16(const void* g, void* l) {
  __builtin_amdgcn_global_load_lds(
      (const __attribute__((address_space(1))) void*)g,
      (__attribute__((address_space(3))) void*)l, 16, 0, 0);
}

// pack two fp32 -> one u32 of two bf16 (lo = a, hi = b)
__device__ __forceinline__ uint32_t pk2(float a, float b) {
  uint16_t ua = __builtin_bit_cast(uint16_t, (bf16)a);
  uint16_t ub = __builtin_bit_cast(uint16_t, (bf16)b);
  return (uint32_t)ua | ((uint32_t)ub << 16);
}

// ---------------- fp32 -> bf16 convert (4 elems/thread) ----------------
__global__ __launch_bounds__(256) void k_cvt(const float* __restrict__ in,
                                             bf16* __restrict__ out, int n) {
  int i = (blockIdx.x * 256 + threadIdx.x) * 4;
  if (i >= n) return;
  float4 v = *(const float4*)(in + i);
  bf16x4 o;
  o[0] = (bf16)v.x; o[1] = (bf16)v.y; o[2] = (bf16)v.z; o[3] = (bf16)v.w;
  *(bf16x4*)(out + i) = o;
}

// ---------------- W (K x N) fp32 -> WT (N x K) bf16 ----------------
__global__ __launch_bounds__(256) void k_transpose(const float* __restrict__ W,
                                                   bf16* __restrict__ WT,
                                                   int K, int N) {
  __shared__ float t[32][33];
  int n0 = blockIdx.x * 32, k0 = blockIdx.y * 32;
  int tx = threadIdx.x & 31, ty = threadIdx.x >> 5;  // 32 x 8
#pragma unroll
  for (int i = 0; i < 4; i++)
    t[ty + 8 * i][tx] = W[(size_t)(k0 + ty + 8 * i) * N + n0 + tx];
  __syncthreads();
#pragma unroll
  for (int i = 0; i < 4; i++)
    WT[(size_t)(n0 + ty + 8 * i) * K + k0 + tx] = (bf16)t[tx][ty + 8 * i];
}

// ---------------- bf16 GEMM: C = A(MxK) @ BT(NxK)^T ----------------
// MODE 2: C fp32 + bias                           (output projection)
// MODE 3: fused QKV: col<1024 -> Q bf16 * scale; col in [1024,1088) -> K bf16
//         (C2); col >= 1088 -> V bf16 stored transposed per batch (C3)
// r10 lesson: 128x128 tiles gave only 288/256 blocks (~1.1/CU, 1 wave/SIMD on
// half the CUs -> no latency hiding, ~400 TF effective). 128x64 doubles the
// grid (2.25/CU, 4+ resident) for better overlap + smaller tail.
template <int BM, int BN, int WM, int WN, int MODE>
__global__ __launch_bounds__(256) void k_gemm(const bf16* __restrict__ A,
                                              const bf16* __restrict__ BT,
                                              void* __restrict__ C,
                                              void* __restrict__ C2,
                                              void* __restrict__ C3,
                                              const float* __restrict__ bias,
                                              int M, int N, int K, float scale) {
  __shared__ __align__(16) char As[BM * 128];
  __shared__ __align__(16) char Bs[BN * 128];
  const int lane = threadIdx.x & 63;
  const int wv = threadIdx.x >> 6;
  constexpr int NWC = BN / WN;
  const int wr = wv / NWC, wc = wv % NWC;
  const int g = lane >> 4, l15 = lane & 15;
  const int m0 = blockIdx.y * BM, n0 = blockIdx.x * BN;
  constexpr int MI = WM / 16, NI = WN / 16;

  f32x4 acc[MI][NI] = {};

  const int srow = lane >> 3;   // staging row within 8-row chunk
  const int c16 = lane & 7;     // staging 16B-column within row

  for (int kt = 0; kt < K; kt += 64) {
    // stage A tile (BM x 64 bf16), XOR-swizzled source, linear LDS dest
#pragma unroll
    for (int j = wv; j < BM / 8; j += 4) {
      int row = j * 8 + srow;
      const char* src = (const char*)A + (size_t)(m0 + row) * (K * 2) + kt * 2 +
                        ((c16 ^ (row & 7)) << 4);
      load_lds16(src, As + j * 1024);
    }
#pragma unroll
    for (int j = wv; j < BN / 8; j += 4) {
      int row = j * 8 + srow;
      const char* src = (const char*)BT + (size_t)(n0 + row) * (K * 2) + kt * 2 +
                        ((c16 ^ (row & 7)) << 4);
      load_lds16(src, Bs + j * 1024);
    }
    __syncthreads();
#pragma unroll
    for (int kk = 0; kk < 2; kk++) {
      bf16x8 af[MI], bfr[NI];
#pragma unroll
      for (int mi = 0; mi < MI; mi++) {
        int row = wr * WM + mi * 16 + l15;
        af[mi] = *(const bf16x8*)(As + row * 128 + (((kk * 4 + g) ^ (row & 7)) << 4));
      }
#pragma unroll
      for (int ni = 0; ni < NI; ni++) {
        int row = wc * WN + ni * 16 + l15;
        bfr[ni] = *(const bf16x8*)(Bs + row * 128 + (((kk * 4 + g) ^ (row & 7)) << 4));
      }
#pragma unroll
      for (int mi = 0; mi < MI; mi++)
#pragma unroll
        for (int ni = 0; ni < NI; ni++)
          acc[mi][ni] = __builtin_amdgcn_mfma_f32_16x16x32_bf16(af[mi], bfr[ni],
                                                                acc[mi][ni], 0, 0, 0);
    }
    __syncthreads();
  }

#pragma unroll
  for (int mi = 0; mi < MI; mi++)
#pragma unroll
    for (int ni = 0; ni < NI; ni++) {
      int col = n0 + wc * WN + ni * 16 + l15;
      int rowb = m0 + wr * WM + mi * 16 + g * 4;
      if (MODE == 2) {
        float bv = bias[col];
#pragma unroll
        for (int r = 0; r < 4; r++)
          ((float*)C)[(size_t)(rowb + r) * N + col] = acc[mi][ni][r] + bv;
      } else {  // MODE 3: fused QKV epilogue
        if (col < 1024) {
#pragma unroll
          for (int r = 0; r < 4; r++)
            ((bf16*)C)[(size_t)(rowb + r) * 1024 + col] =
                (bf16)(acc[mi][ni][r] * scale);
        } else if (col < 1088) {
#pragma unroll
          for (int r = 0; r < 4; r++)
            ((bf16*)C2)[(size_t)(rowb + r) * 64 + (col - 1024)] =
                (bf16)acc[mi][ni][r];
        } else {
#pragma unroll
          for (int r = 0; r < 4; r++) {
            int m = rowb + r;
            ((bf16*)C3)[((size_t)((m >> 11) * 64 + (col - 1088))) * 2048 +
                        (m & 2047)] = (bf16)acc[mi][ni][r];
          }
        }
      }
    }
}

// ---- fused attention: 8-wave blocks, shared LDS K/V tiles, 2-phase dbuf ----
// Q: (B*SEQ,1024) bf16 pre-scaled; K: (B*SEQ,64) bf16; VT: (B,64,SEQ) bf16.
// grid = B * H * (SEQ/128) = 512 blocks; block = 8 waves = 4 qsub x 2 kvhalf.
// Each wave: 32 q-rows, 1 head, over its kv-half; the FOUR q-waves of a
// kv-half share one staged K/V tile pair (16 KB), each staging 4 KB.
// 2-phase pipeline: STAGE(other buf, t+1) issued BEFORE compute(buf); the
// single __syncthreads per tile drains vmcnt AFTER a full compute phase.
// r11: kv-loop unrolled x2 with STATIC buffer bases (the (t&1) dynamic base
// forced per-tile re-derivation of all 16 ds_read addrs; static lets the
// compiler fold buffer choice into the 16-bit offset: immediate) + s_setprio
// around MFMA clusters (T5, +4-7% attn per guide m191).
// Swapped QK (mfma(K,Q) -> S^T): softmax lane-local; pk2+permlane32_swap
// builds PV A-frags in-register.
// REGISTER BUDGET (r4/r5/r7 lessons): (512,4) caps the unified pool at 128;
// r9/r10 compiled clean under it (60-64 arch). Tripwire = WRITE_SIZE >> 8 MB.
__global__ __launch_bounds__(512, 4) void k_attn(const bf16* __restrict__ Q,
                                                 const bf16* __restrict__ K,
                                                 const bf16* __restrict__ VT,
                                                 bf16* __restrict__ O) {
  // [buf 0/1][kh 0/1][K 8KB | V 8KB] = 64 KB; merge reuses after final barrier
  __shared__ __align__(16) char smem[65536];
  int bid = blockIdx.x;
  int q128 = bid & 15;
  int h = (bid >> 4) & 15;
  int b = bid >> 8;
  int wv = threadIdx.x >> 6, lane = threadIdx.x & 63;
  int l31 = lane & 31, hi = lane >> 5;
  int qs = wv & 3, kh = wv >> 2;
  int q0 = q128 * 128 + qs * 32;

  // Q B-frags: lane holds Q[q=q0+l31][d = f*16 + hi*8 + j]
  const bf16* qrow =
      Q + ((size_t)(b * SEQ + q0 + l31) * NDIM + h * HD + hi * 8);
  bf16x8 aq[4];
#pragma unroll
  for (int f = 0; f < 4; f++) aq[f] = *(const bf16x8*)(qrow + f * 16);

  const int srow = lane >> 3, c16 = lane & 7;
  const int kvbeg = kh * (SEQ / 2);

  // stage tile t (64 kv) into buffer bb: this wave stages chunks qs*4..qs*4+3
  // (chunk<8: K rows chunk*8.., chunk>=8: V rows (chunk-8)*8..); 1KB each.
  auto stage = [&](int bb, int t) {
    char* base = smem + bb * 32768 + kh * 16384;
    const int kv0 = kvbeg + t * 64;
#pragma unroll
    for (int j = 0; j < 4; j++) {
      int c = qs * 4 + j;
      if (c < 8) {
        const char* src = (const char*)K +
                          (size_t)(b * SEQ + kv0 + c * 8 + srow) * 128 +
                          ((c16 ^ srow) << 4);
        load_lds16(src, base + c * 1024);
      } else {
        const char* src = (const char*)VT +
                          (size_t)(b * 64 + (c - 8) * 8 + srow) * (SEQ * 2) +
                          (size_t)kv0 * 2 + ((c16 ^ srow) << 4);
        load_lds16(src, base + c * 1024);
      }
    }
  };

  f32x16 acc[2] = {};  // [dc]; lane: O[q=(r&3)+8(r>>2)+4hi][d=dc*32+l31]
  float lsum = 0.f;

  // compute one staged 64-kv tile at a STATIC buffer base
  auto compute = [&](char* Kl, char* Vl) {
#pragma unroll
    for (int kvb = 0; kvb < 2; kvb++) {
      bf16x8 kf[4];
#pragma unroll
      for (int f = 0; f < 4; f++)
        kf[f] = *(const bf16x8*)(Kl + (kvb * 32 + l31) * 128 +
                                 (((f * 2 + hi) ^ (l31 & 7)) << 4));
      f32x16 s = {};
      __builtin_amdgcn_s_setprio(1);
#pragma unroll
      for (int f = 0; f < 4; f++)
        s = __builtin_amdgcn_mfma_f32_32x32x16_bf16(kf[f], aq[f], s, 0, 0, 0);
      __builtin_amdgcn_s_setprio(0);
      float p[16];
#pragma unroll
      for (int i = 0; i < 16; i++) {
        p[i] = __builtin_amdgcn_exp2f(s[i]);
        lsum += p[i];
      }
#pragma unroll
      for (int n = 0; n < 2; n++) {
        uint32_t t0 = pk2(p[8 * n + 0], p[8 * n + 1]);
        uint32_t t1 = pk2(p[8 * n + 2], p[8 * n + 3]);
        uint32_t t2 = pk2(p[8 * n + 4], p[8 * n + 5]);
        uint32_t t3 = pk2(p[8 * n + 6], p[8 * n + 7]);
        u32x2 rA = __builtin_amdgcn_permlane32_swap(t0, t2, false, false);
        u32x2 rB = __builtin_amdgcn_permlane32_swap(t1, t3, false, false);
        union { uint32_t u[4]; bf16x8 v; } af;
        af.u[0] = rA[0]; af.u[1] = rB[0]; af.u[2] = rA[1]; af.u[3] = rB[1];
        __builtin_amdgcn_s_setprio(1);
#pragma unroll
        for (int dc = 0; dc < 2; dc++) {
          bf16x8 vf = *(const bf16x8*)(Vl + (dc * 32 + l31) * 128 +
                                       (((kvb * 4 + n * 2 + hi) ^ (l31 & 7))
                                        << 4));
          acc[dc] = __builtin_amdgcn_mfma_f32_32x32x16_bf16(af.v, vf, acc[dc],
                                                            0, 0, 0);
        }
        __builtin_amdgcn_s_setprio(0);
      }
    }
  };

  char* K0 = smem + kh * 16384;
  char* V0 = K0 + 8192;
  char* K1 = smem + 32768 + kh * 16384;
  char* V1 = K1 + 8192;

  stage(0, 0);
  __syncthreads();

#pragma unroll 1
  for (int t = 0; t < 16; t += 2) {
    stage(1, t + 1);            // always valid: t+1 <= 15
    compute(K0, V0);
    __syncthreads();
    if (t + 2 < 16) stage(0, t + 2);
    compute(K1, V1);
    __syncthreads();
  }

  // combine the two hi-halves of each q's row sum (lane-local otherwise)
  lsum += __shfl_xor(lsum, 32, 64);

  // merge the two kv-halves: kh=1 writes partials, kh=0 adds + outputs.
  float* mb = (float*)smem;  // [4 qs][64 lanes][33 f32] = 33792 B
  if (kh == 1) {
    float* dst = mb + ((size_t)(qs * 64 + lane)) * 33;
#pragma unroll
    for (int dc = 0; dc < 2; dc++)
#pragma unroll
      for (int r = 0; r < 16; r++) dst[dc * 16 + r] = acc[dc][r];
    dst[32] = lsum;
  }
  __syncthreads();
  if (kh == 0) {
    const float* src = mb + ((size_t)(qs * 64 + lane)) * 33;
#pragma unroll
    for (int dc = 0; dc < 2; dc++)
#pragma unroll
      for (int r = 0; r < 16; r++) acc[dc][r] += src[dc * 16 + r];
    lsum += src[32];
#pragma unroll
    for (int r = 0; r < 16; r++) {
      int q_r = (r & 3) + 8 * (r >> 2) + 4 * hi;
      float ls = __shfl(lsum, q_r, 64);
      float rinv = 1.0f / ls;
#pragma unroll
      for (int dc = 0; dc < 2; dc++)
        O[(size_t)(b * SEQ + q0 + q_r) * NDIM + h * HD + dc * 32 + l31] =
            (bf16)(acc[dc][r] * rinv);
    }
  }
}

extern "C" void kernel_launch(void* const* d_in, const int* in_sizes, int n_in,
                              void* d_out, int out_size, void* d_ws, size_t ws_size,
                              hipStream_t stream) {
  const float* x = (const float*)d_in[0];
  const float* Wq = (const float*)d_in[1];
  const float* Wk = (const float*)d_in[2];
  const float* Wv = (const float*)d_in[3];
  const float* Wp = (const float*)d_in[4];
  const float* bp = (const float*)d_in[5];
  float* out = (float*)d_out;

  size_t off = 0;
  char* wsb = (char*)d_ws;
  auto alloc = [&](size_t bytes) {
    char* p = wsb + off;
    off += bytes;
    return p;
  };
  bf16* x_bf = (bf16*)alloc((size_t)4096 * 1024 * 2);
  bf16* wqkvT = (bf16*)alloc((size_t)1152 * 1024 * 2);  // [WqT;WkT;WvT]
  bf16* wpT = (bf16*)alloc((size_t)1024 * 1024 * 2);
  bf16* Qb = (bf16*)alloc((size_t)4096 * 1024 * 2);
  bf16* Kb = (bf16*)alloc((size_t)4096 * 64 * 2);
  bf16* VTb = (bf16*)alloc((size_t)2 * 64 * 2048 * 2);
  bf16* AOb = (bf16*)alloc((size_t)4096 * 1024 * 2);

  k_cvt<<<4096, 256, 0, stream>>>(x, x_bf, 4096 * 1024);
  k_transpose<<<dim3(32, 32), 256, 0, stream>>>(Wq, wqkvT, 1024, 1024);
  k_transpose<<<dim3(2, 32), 256, 0, stream>>>(Wk, wqkvT + (size_t)1024 * 1024,
                                               1024, 64);
  k_transpose<<<dim3(2, 32), 256, 0, stream>>>(Wv, wqkvT + (size_t)1088 * 1024,
                                               1024, 64);
  k_transpose<<<dim3(32, 32), 256, 0, stream>>>(Wp, wpT, 1024, 1024);

  // fused Q/K/V projection: N = 1152 = 1024(Q) + 64(K) + 64(V)
  k_gemm<128, 64, 64, 32, 3><<<dim3(18, 32), 256, 0, stream>>>(
      x_bf, wqkvT, Qb, Kb, VTb, nullptr, 4096, 1152, 1024, QSCALE);

  k_attn<<<512, 512, 0, stream>>>(Qb, Kb, VTb, AOb);

  // output projection + bias, fp32 out
  k_gemm<128, 64, 64, 32, 2><<<dim3(16, 32), 256, 0, stream>>>(
      AOb, wpT, out, nullptr, nullptr, bp, 4096, 1024, 1024, 1.0f);
}

// Round 12
// 101.726 us; speedup vs baseline: 2.0004x; 1.0120x over previous
//
#include <hip/hip_runtime.h>
#include <hip/hip_bf16.h>
#include <stdint.h>

using bf16 = __bf16;
using bf16x4 = __attribute__((ext_vector_type(4))) __bf16;
using bf16x8 = __attribute__((ext_vector_type(8))) __bf16;
using f32x4 = __attribute__((ext_vector_type(4))) float;
using f32x16 = __attribute__((ext_vector_type(16))) float;
using u32x2 = __attribute__((ext_vector_type(2))) unsigned int;

static constexpr int SEQ = 2048;
static constexpr int NDIM = 1024;
static constexpr int NHEAD = 16;
static constexpr int HD = 64;
// fold softmax scale and log2(e) into Q so scores are already in log2 domain
static constexpr float QSCALE = 0.125f * 1.4426950408889634f;

__device__ __forceinline__ void load_lds16(const void* g, void* l) {
  __builtin_amdgcn_global_load_lds(
      (const __attribute__((address_space(1))) void*)g,
      (__attribute__((address_space(3))) void*)l, 16, 0, 0);
}

// pack two fp32 -> one u32 of two bf16 (lo = a, hi = b)
__device__ __forceinline__ uint32_t pk2(float a, float b) {
  uint16_t ua = __builtin_bit_cast(uint16_t, (bf16)a);
  uint16_t ub = __builtin_bit_cast(uint16_t, (bf16)b);
  return (uint32_t)ua | ((uint32_t)ub << 16);
}

// ---- fused prep: x fp32->bf16 (blocks 0..4095) + 4 weight transposes ------
// (r12: was 5 dispatches; fusing removes 4 launch gaps/tails)
__global__ __launch_bounds__(256) void k_prep(const float* __restrict__ x,
                                              const float* __restrict__ Wq,
                                              const float* __restrict__ Wk,
                                              const float* __restrict__ Wv,
                                              const float* __restrict__ Wp,
                                              bf16* __restrict__ x_bf,
                                              bf16* __restrict__ wqkvT,
                                              bf16* __restrict__ wpT) {
  __shared__ float t[32][33];
  int bid = blockIdx.x;
  if (bid < 4096) {  // cvt: 4096 blocks x 256 thr x 4 elems = 4096*1024
    int i = (bid * 256 + threadIdx.x) * 4;
    float4 v = *(const float4*)(x + i);
    bf16x4 o;
    o[0] = (bf16)v.x; o[1] = (bf16)v.y; o[2] = (bf16)v.z; o[3] = (bf16)v.w;
    *(bf16x4*)(x_bf + i) = o;
    return;
  }
  const float* W; bf16* WT; int N; int idx;
  if (bid < 5120)      { W = Wq; WT = wqkvT;                         N = 1024; idx = bid - 4096; }
  else if (bid < 5184) { W = Wk; WT = wqkvT + (size_t)1024 * 1024;   N = 64;   idx = bid - 5120; }
  else if (bid < 5248) { W = Wv; WT = wqkvT + (size_t)1088 * 1024;   N = 64;   idx = bid - 5184; }
  else                 { W = Wp; WT = wpT;                           N = 1024; idx = bid - 5248; }
  const int nb = N / 32;
  const int n0 = (idx % nb) * 32, k0 = (idx / nb) * 32;
  const int tx = threadIdx.x & 31, ty = threadIdx.x >> 5;  // 32 x 8
#pragma unroll
  for (int i = 0; i < 4; i++)
    t[ty + 8 * i][tx] = W[(size_t)(k0 + ty + 8 * i) * N + n0 + tx];
  __syncthreads();
#pragma unroll
  for (int i = 0; i < 4; i++)
    WT[(size_t)(n0 + ty + 8 * i) * 1024 + k0 + tx] = (bf16)t[tx][ty + 8 * i];
}

// ---------------- bf16 GEMM: C = A(MxK) @ BT(NxK)^T ----------------
// MODE 2: C fp32 + bias                           (output projection)
// MODE 3: fused QKV: col<1024 -> Q bf16 * scale; col in [1024,1088) -> K bf16
//         (C2); col >= 1088 -> V bf16 stored transposed per batch (C3)
// 128x64 tile: grid 576/512 blocks (~2.25/CU resident) -- r11 win vs 128x128.
template <int BM, int BN, int WM, int WN, int MODE>
__global__ __launch_bounds__(256) void k_gemm(const bf16* __restrict__ A,
                                              const bf16* __restrict__ BT,
                                              void* __restrict__ C,
                                              void* __restrict__ C2,
                                              void* __restrict__ C3,
                                              const float* __restrict__ bias,
                                              int M, int N, int K, float scale) {
  __shared__ __align__(16) char As[BM * 128];
  __shared__ __align__(16) char Bs[BN * 128];
  const int lane = threadIdx.x & 63;
  const int wv = threadIdx.x >> 6;
  constexpr int NWC = BN / WN;
  const int wr = wv / NWC, wc = wv % NWC;
  const int g = lane >> 4, l15 = lane & 15;
  const int m0 = blockIdx.y * BM, n0 = blockIdx.x * BN;
  constexpr int MI = WM / 16, NI = WN / 16;

  f32x4 acc[MI][NI] = {};

  const int srow = lane >> 3;   // staging row within 8-row chunk
  const int c16 = lane & 7;     // staging 16B-column within row

  for (int kt = 0; kt < K; kt += 64) {
#pragma unroll
    for (int j = wv; j < BM / 8; j += 4) {
      int row = j * 8 + srow;
      const char* src = (const char*)A + (size_t)(m0 + row) * (K * 2) + kt * 2 +
                        ((c16 ^ (row & 7)) << 4);
      load_lds16(src, As + j * 1024);
    }
#pragma unroll
    for (int j = wv; j < BN / 8; j += 4) {
      int row = j * 8 + srow;
      const char* src = (const char*)BT + (size_t)(n0 + row) * (K * 2) + kt * 2 +
                        ((c16 ^ (row & 7)) << 4);
      load_lds16(src, Bs + j * 1024);
    }
    __syncthreads();
#pragma unroll
    for (int kk = 0; kk < 2; kk++) {
      bf16x8 af[MI], bfr[NI];
#pragma unroll
      for (int mi = 0; mi < MI; mi++) {
        int row = wr * WM + mi * 16 + l15;
        af[mi] = *(const bf16x8*)(As + row * 128 + (((kk * 4 + g) ^ (row & 7)) << 4));
      }
#pragma unroll
      for (int ni = 0; ni < NI; ni++) {
        int row = wc * WN + ni * 16 + l15;
        bfr[ni] = *(const bf16x8*)(Bs + row * 128 + (((kk * 4 + g) ^ (row & 7)) << 4));
      }
#pragma unroll
      for (int mi = 0; mi < MI; mi++)
#pragma unroll
        for (int ni = 0; ni < NI; ni++)
          acc[mi][ni] = __builtin_amdgcn_mfma_f32_16x16x32_bf16(af[mi], bfr[ni],
                                                                acc[mi][ni], 0, 0, 0);
    }
    __syncthreads();
  }

#pragma unroll
  for (int mi = 0; mi < MI; mi++)
#pragma unroll
    for (int ni = 0; ni < NI; ni++) {
      int col = n0 + wc * WN + ni * 16 + l15;
      int rowb = m0 + wr * WM + mi * 16 + g * 4;
      if (MODE == 2) {
        float bv = bias[col];
#pragma unroll
        for (int r = 0; r < 4; r++)
          ((float*)C)[(size_t)(rowb + r) * N + col] = acc[mi][ni][r] + bv;
      } else {  // MODE 3: fused QKV epilogue
        if (col < 1024) {
#pragma unroll
          for (int r = 0; r < 4; r++)
            ((bf16*)C)[(size_t)(rowb + r) * 1024 + col] =
                (bf16)(acc[mi][ni][r] * scale);
        } else if (col < 1088) {
#pragma unroll
          for (int r = 0; r < 4; r++)
            ((bf16*)C2)[(size_t)(rowb + r) * 64 + (col - 1024)] =
                (bf16)acc[mi][ni][r];
        } else {
#pragma unroll
          for (int r = 0; r < 4; r++) {
            int m = rowb + r;
            ((bf16*)C3)[((size_t)((m >> 11) * 64 + (col - 1088))) * 2048 +
                        (m & 2047)] = (bf16)acc[mi][ni][r];
          }
        }
      }
    }
}

// ---- fused attention: 8-wave blocks, shared LDS K/V tiles, 2-phase dbuf ----
// grid = B * H * (SEQ/128) = 512 blocks; block = 8 waves = 4 qsub x 2 kvhalf.
// r12: per-tile compute restructured for ILP -- r11 showed the binder is the
// in-wave serial chain (QK->exp2->pack->PV) under barrier lockstep (VALUBusy
// 50%, MfmaUtil 26%, ~1930cyc/tile vs ~965 VALU): now both 32-kv halves'
// QK chains issue back-to-back (2 indep 4-MFMA chains), all 32 exp2 together
// (2 indep lsum partials), pack all 4 A-frags, then 8 PV MFMAs as 2 indep
// per-dc chains. Same instrs, ~2x scheduling window.
// REGISTER BUDGET (r4/r5/r7): (512,4) = 128-cap unified. Peak live ~120.
// Tripwire = WRITE_SIZE >> 9 MB means spill: revert.
__global__ __launch_bounds__(512, 4) void k_attn(const bf16* __restrict__ Q,
                                                 const bf16* __restrict__ K,
                                                 const bf16* __restrict__ VT,
                                                 bf16* __restrict__ O) {
  __shared__ __align__(16) char smem[65536];
  int bid = blockIdx.x;
  int q128 = bid & 15;
  int h = (bid >> 4) & 15;
  int b = bid >> 8;
  int wv = threadIdx.x >> 6, lane = threadIdx.x & 63;
  int l31 = lane & 31, hi = lane >> 5;
  int qs = wv & 3, kh = wv >> 2;
  int q0 = q128 * 128 + qs * 32;

  const bf16* qrow =
      Q + ((size_t)(b * SEQ + q0 + l31) * NDIM + h * HD + hi * 8);
  bf16x8 aq[4];
#pragma unroll
  for (int f = 0; f < 4; f++) aq[f] = *(const bf16x8*)(qrow + f * 16);

  const int srow = lane >> 3, c16 = lane & 7;
  const int kvbeg = kh * (SEQ / 2);

  auto stage = [&](int bb, int t) {
    char* base = smem + bb * 32768 + kh * 16384;
    const int kv0 = kvbeg + t * 64;
#pragma unroll
    for (int j = 0; j < 4; j++) {
      int c = qs * 4 + j;
      if (c < 8) {
        const char* src = (const char*)K +
                          (size_t)(b * SEQ + kv0 + c * 8 + srow) * 128 +
                          ((c16 ^ srow) << 4);
        load_lds16(src, base + c * 1024);
      } else {
        const char* src = (const char*)VT +
                          (size_t)(b * 64 + (c - 8) * 8 + srow) * (SEQ * 2) +
                          (size_t)kv0 * 2 + ((c16 ^ srow) << 4);
        load_lds16(src, base + c * 1024);
      }
    }
  };

  f32x16 acc[2] = {};  // [dc]; lane: O[q=(r&3)+8(r>>2)+4hi][d=dc*32+l31]
  float lsa = 0.f, lsb = 0.f;  // two independent row-sum partials

  // build one PV A-frag from 8 consecutive p values (bf16 pack + lane swap)
  auto mkfrag = [&](const float* p) {
    uint32_t t0 = pk2(p[0], p[1]);
    uint32_t t1 = pk2(p[2], p[3]);
    uint32_t t2 = pk2(p[4], p[5]);
    uint32_t t3 = pk2(p[6], p[7]);
    u32x2 rA = __builtin_amdgcn_permlane32_swap(t0, t2, false, false);
    u32x2 rB = __builtin_amdgcn_permlane32_swap(t1, t3, false, false);
    union { uint32_t u[4]; bf16x8 v; } af;
    af.u[0] = rA[0]; af.u[1] = rB[0]; af.u[2] = rA[1]; af.u[3] = rB[1];
    return af.v;
  };

  // compute one staged 64-kv tile, ILP-restructured
  auto compute = [&](char* Kl, char* Vl) {
    bf16x8 kf0[4], kf1[4];
#pragma unroll
    for (int f = 0; f < 4; f++) {
      kf0[f] = *(const bf16x8*)(Kl + l31 * 128 + (((f * 2 + hi) ^ (l31 & 7)) << 4));
      kf1[f] = *(const bf16x8*)(Kl + (32 + l31) * 128 + (((f * 2 + hi) ^ (l31 & 7)) << 4));
    }
    f32x16 s0 = {}, s1 = {};
    __builtin_amdgcn_s_setprio(1);
#pragma unroll
    for (int f = 0; f < 4; f++) {
      s0 = __builtin_amdgcn_mfma_f32_32x32x16_bf16(kf0[f], aq[f], s0, 0, 0, 0);
      s1 = __builtin_amdgcn_mfma_f32_32x32x16_bf16(kf1[f], aq[f], s1, 0, 0, 0);
    }
    __builtin_amdgcn_s_setprio(0);
    float p0[16], p1[16];
#pragma unroll
    for (int i = 0; i < 16; i++) {
      p0[i] = __builtin_amdgcn_exp2f(s0[i]);
      p1[i] = __builtin_amdgcn_exp2f(s1[i]);
    }
#pragma unroll
    for (int i = 0; i < 16; i++) {
      lsa += p0[i];
      lsb += p1[i];
    }
    bf16x8 pa[4];  // m = kvb*2+n; kv position = m*16 + hi*8 + j
    pa[0] = mkfrag(p0);
    pa[1] = mkfrag(p0 + 8);
    pa[2] = mkfrag(p1);
    pa[3] = mkfrag(p1 + 8);
    __builtin_amdgcn_s_setprio(1);
#pragma unroll
    for (int m = 0; m < 4; m++)
#pragma unroll
      for (int dc = 0; dc < 2; dc++) {
        bf16x8 vf = *(const bf16x8*)(Vl + (dc * 32 + l31) * 128 +
                                     (((m * 2 + hi) ^ (l31 & 7)) << 4));
        acc[dc] = __builtin_amdgcn_mfma_f32_32x32x16_bf16(pa[m], vf, acc[dc],
                                                          0, 0, 0);
      }
    __builtin_amdgcn_s_setprio(0);
  };

  char* K0 = smem + kh * 16384;
  char* V0 = K0 + 8192;
  char* K1 = smem + 32768 + kh * 16384;
  char* V1 = K1 + 8192;

  stage(0, 0);
  __syncthreads();

#pragma unroll 1
  for (int t = 0; t < 16; t += 2) {
    stage(1, t + 1);            // always valid: t+1 <= 15
    compute(K0, V0);
    __syncthreads();
    if (t + 2 < 16) stage(0, t + 2);
    compute(K1, V1);
    __syncthreads();
  }

  float lsum = lsa + lsb;
  lsum += __shfl_xor(lsum, 32, 64);

  // merge the two kv-halves: kh=1 writes partials, kh=0 adds + outputs.
  float* mb = (float*)smem;  // [4 qs][64 lanes][33 f32] = 33792 B
  if (kh == 1) {
    float* dst = mb + ((size_t)(qs * 64 + lane)) * 33;
#pragma unroll
    for (int dc = 0; dc < 2; dc++)
#pragma unroll
      for (int r = 0; r < 16; r++) dst[dc * 16 + r] = acc[dc][r];
    dst[32] = lsum;
  }
  __syncthreads();
  if (kh == 0) {
    const float* src = mb + ((size_t)(qs * 64 + lane)) * 33;
#pragma unroll
    for (int dc = 0; dc < 2; dc++)
#pragma unroll
      for (int r = 0; r < 16; r++) acc[dc][r] += src[dc * 16 + r];
    lsum += src[32];
#pragma unroll
    for (int r = 0; r < 16; r++) {
      int q_r = (r & 3) + 8 * (r >> 2) + 4 * hi;
      float ls = __shfl(lsum, q_r, 64);
      float rinv = 1.0f / ls;
#pragma unroll
      for (int dc = 0; dc < 2; dc++)
        O[(size_t)(b * SEQ + q0 + q_r) * NDIM + h * HD + dc * 32 + l31] =
            (bf16)(acc[dc][r] * rinv);
    }
  }
}

extern "C" void kernel_launch(void* const* d_in, const int* in_sizes, int n_in,
                              void* d_out, int out_size, void* d_ws, size_t ws_size,
                              hipStream_t stream) {
  const float* x = (const float*)d_in[0];
  const float* Wq = (const float*)d_in[1];
  const float* Wk = (const float*)d_in[2];
  const float* Wv = (const float*)d_in[3];
  const float* Wp = (const float*)d_in[4];
  const float* bp = (const float*)d_in[5];
  float* out = (float*)d_out;

  size_t off = 0;
  char* wsb = (char*)d_ws;
  auto alloc = [&](size_t bytes) {
    char* p = wsb + off;
    off += bytes;
    return p;
  };
  bf16* x_bf = (bf16*)alloc((size_t)4096 * 1024 * 2);
  bf16* wqkvT = (bf16*)alloc((size_t)1152 * 1024 * 2);  // [WqT;WkT;WvT]
  bf16* wpT = (bf16*)alloc((size_t)1024 * 1024 * 2);
  bf16* Qb = (bf16*)alloc((size_t)4096 * 1024 * 2);
  bf16* Kb = (bf16*)alloc((size_t)4096 * 64 * 2);
  bf16* VTb = (bf16*)alloc((size_t)2 * 64 * 2048 * 2);
  bf16* AOb = (bf16*)alloc((size_t)4096 * 1024 * 2);

  // fused prep: cvt (4096 blocks) + Wq (1024) + Wk (64) + Wv (64) + Wp (1024)
  k_prep<<<6272, 256, 0, stream>>>(x, Wq, Wk, Wv, Wp, x_bf, wqkvT, wpT);

  // fused Q/K/V projection: N = 1152 = 1024(Q) + 64(K) + 64(V)
  k_gemm<128, 64, 64, 32, 3><<<dim3(18, 32), 256, 0, stream>>>(
      x_bf, wqkvT, Qb, Kb, VTb, nullptr, 4096, 1152, 1024, QSCALE);

  k_attn<<<512, 512, 0, stream>>>(Qb, Kb, VTb, AOb);

  // output projection + bias, fp32 out
  k_gemm<128, 64, 64, 32, 2><<<dim3(16, 32), 256, 0, stream>>>(
      AOb, wpT, out, nullptr, nullptr, bp, 4096, 1024, 1024, 1.0f);
}

// Round 13
// 95.102 us; speedup vs baseline: 2.1397x; 1.0697x over previous
//
#include <hip/hip_runtime.h>
#include <hip/hip_bf16.h>
#include <stdint.h>

using bf16 = __bf16;
using bf16x4 = __attribute__((ext_vector_type(4))) __bf16;
using bf16x8 = __attribute__((ext_vector_type(8))) __bf16;
using f32x4 = __attribute__((ext_vector_type(4))) float;
using f32x16 = __attribute__((ext_vector_type(16))) float;
using u32x2 = __attribute__((ext_vector_type(2))) unsigned int;

static constexpr int SEQ = 2048;
static constexpr int NDIM = 1024;
static constexpr int NHEAD = 16;
static constexpr int HD = 64;
// fold softmax scale and log2(e) into Q so scores are already in log2 domain
static constexpr float QSCALE = 0.125f * 1.4426950408889634f;

__device__ __forceinline__ void load_lds16(const void* g, void* l) {
  __builtin_amdgcn_global_load_lds(
      (const __attribute__((address_space(1))) void*)g,
      (__attribute__((address_space(3))) void*)l, 16, 0, 0);
}

// pack two fp32 -> one u32 of two bf16 (lo = a, hi = b)
__device__ __forceinline__ uint32_t pk2(float a, float b) {
  uint16_t ua = __builtin_bit_cast(uint16_t, (bf16)a);
  uint16_t ub = __builtin_bit_cast(uint16_t, (bf16)b);
  return (uint32_t)ua | ((uint32_t)ub << 16);
}

// ---- fused prep: x fp32->bf16 (blocks 0..4095) + 4 weight transposes ------
// (r12 win: was 5 dispatches; fusing removed 4 launch gaps/tails, ~12 us)
__global__ __launch_bounds__(256) void k_prep(const float* __restrict__ x,
                                              const float* __restrict__ Wq,
                                              const float* __restrict__ Wk,
                                              const float* __restrict__ Wv,
                                              const float* __restrict__ Wp,
                                              bf16* __restrict__ x_bf,
                                              bf16* __restrict__ wqkvT,
                                              bf16* __restrict__ wpT) {
  __shared__ float t[32][33];
  int bid = blockIdx.x;
  if (bid < 4096) {  // cvt: 4096 blocks x 256 thr x 4 elems = 4096*1024
    int i = (bid * 256 + threadIdx.x) * 4;
    float4 v = *(const float4*)(x + i);
    bf16x4 o;
    o[0] = (bf16)v.x; o[1] = (bf16)v.y; o[2] = (bf16)v.z; o[3] = (bf16)v.w;
    *(bf16x4*)(x_bf + i) = o;
    return;
  }
  const float* W; bf16* WT; int N; int idx;
  if (bid < 5120)      { W = Wq; WT = wqkvT;                         N = 1024; idx = bid - 4096; }
  else if (bid < 5184) { W = Wk; WT = wqkvT + (size_t)1024 * 1024;   N = 64;   idx = bid - 5120; }
  else if (bid < 5248) { W = Wv; WT = wqkvT + (size_t)1088 * 1024;   N = 64;   idx = bid - 5184; }
  else                 { W = Wp; WT = wpT;                           N = 1024; idx = bid - 5248; }
  const int nb = N / 32;
  const int n0 = (idx % nb) * 32, k0 = (idx / nb) * 32;
  const int tx = threadIdx.x & 31, ty = threadIdx.x >> 5;  // 32 x 8
#pragma unroll
  for (int i = 0; i < 4; i++)
    t[ty + 8 * i][tx] = W[(size_t)(k0 + ty + 8 * i) * N + n0 + tx];
  __syncthreads();
#pragma unroll
  for (int i = 0; i < 4; i++)
    WT[(size_t)(n0 + ty + 8 * i) * 1024 + k0 + tx] = (bf16)t[tx][ty + 8 * i];
}

// ---------------- bf16 GEMM: C = A(MxK) @ BT(NxK)^T ----------------
// MODE 2: C fp32 + bias                           (output projection)
// MODE 3: fused QKV: col<1024 -> Q bf16 * scale; col in [1024,1088) -> K bf16
//         (C2); col >= 1088 -> V bf16 stored transposed per batch (C3)
// 128x64 tile: grid 576/512 blocks (~2.25/CU resident) -- r11 win vs 128x128.
template <int BM, int BN, int WM, int WN, int MODE>
__global__ __launch_bounds__(256) void k_gemm(const bf16* __restrict__ A,
                                              const bf16* __restrict__ BT,
                                              void* __restrict__ C,
                                              void* __restrict__ C2,
                                              void* __restrict__ C3,
                                              const float* __restrict__ bias,
                                              int M, int N, int K, float scale) {
  __shared__ __align__(16) char As[BM * 128];
  __shared__ __align__(16) char Bs[BN * 128];
  const int lane = threadIdx.x & 63;
  const int wv = threadIdx.x >> 6;
  constexpr int NWC = BN / WN;
  const int wr = wv / NWC, wc = wv % NWC;
  const int g = lane >> 4, l15 = lane & 15;
  const int m0 = blockIdx.y * BM, n0 = blockIdx.x * BN;
  constexpr int MI = WM / 16, NI = WN / 16;

  f32x4 acc[MI][NI] = {};

  const int srow = lane >> 3;   // staging row within 8-row chunk
  const int c16 = lane & 7;     // staging 16B-column within row

  for (int kt = 0; kt < K; kt += 64) {
#pragma unroll
    for (int j = wv; j < BM / 8; j += 4) {
      int row = j * 8 + srow;
      const char* src = (const char*)A + (size_t)(m0 + row) * (K * 2) + kt * 2 +
                        ((c16 ^ (row & 7)) << 4);
      load_lds16(src, As + j * 1024);
    }
#pragma unroll
    for (int j = wv; j < BN / 8; j += 4) {
      int row = j * 8 + srow;
      const char* src = (const char*)BT + (size_t)(n0 + row) * (K * 2) + kt * 2 +
                        ((c16 ^ (row & 7)) << 4);
      load_lds16(src, Bs + j * 1024);
    }
    __syncthreads();
#pragma unroll
    for (int kk = 0; kk < 2; kk++) {
      bf16x8 af[MI], bfr[NI];
#pragma unroll
      for (int mi = 0; mi < MI; mi++) {
        int row = wr * WM + mi * 16 + l15;
        af[mi] = *(const bf16x8*)(As + row * 128 + (((kk * 4 + g) ^ (row & 7)) << 4));
      }
#pragma unroll
      for (int ni = 0; ni < NI; ni++) {
        int row = wc * WN + ni * 16 + l15;
        bfr[ni] = *(const bf16x8*)(Bs + row * 128 + (((kk * 4 + g) ^ (row & 7)) << 4));
      }
#pragma unroll
      for (int mi = 0; mi < MI; mi++)
#pragma unroll
        for (int ni = 0; ni < NI; ni++)
          acc[mi][ni] = __builtin_amdgcn_mfma_f32_16x16x32_bf16(af[mi], bfr[ni],
                                                                acc[mi][ni], 0, 0, 0);
    }
    __syncthreads();
  }

#pragma unroll
  for (int mi = 0; mi < MI; mi++)
#pragma unroll
    for (int ni = 0; ni < NI; ni++) {
      int col = n0 + wc * WN + ni * 16 + l15;
      int rowb = m0 + wr * WM + mi * 16 + g * 4;
      if (MODE == 2) {
        float bv = bias[col];
#pragma unroll
        for (int r = 0; r < 4; r++)
          ((float*)C)[(size_t)(rowb + r) * N + col] = acc[mi][ni][r] + bv;
      } else {  // MODE 3: fused QKV epilogue
        if (col < 1024) {
#pragma unroll
          for (int r = 0; r < 4; r++)
            ((bf16*)C)[(size_t)(rowb + r) * 1024 + col] =
                (bf16)(acc[mi][ni][r] * scale);
        } else if (col < 1088) {
#pragma unroll
          for (int r = 0; r < 4; r++)
            ((bf16*)C2)[(size_t)(rowb + r) * 64 + (col - 1024)] =
                (bf16)acc[mi][ni][r];
        } else {
#pragma unroll
          for (int r = 0; r < 4; r++) {
            int m = rowb + r;
            ((bf16*)C3)[((size_t)((m >> 11) * 64 + (col - 1088))) * 2048 +
                        (m & 2047)] = (bf16)acc[mi][ni][r];
          }
        }
      }
    }
}

// ---- fused attention: 8-wave blocks, shared LDS K/V tiles, 2-phase dbuf ----
// grid = B * H * (SEQ/128) = 512 blocks; block = 8 waves = 4 qsub x 2 kvhalf.
// r13: REVERTED r12's ILP restructure -- live-set math: kf0+kf1(64)+s0+s1(32)
// +acc(32)+aq(16) = 144 > 128 cap -> in-loop scratch spill (WRITE 9.2->20.5
// MB, dur 51.5->62 us). This sequential form is the measured best (51.5 us,
// 64 arch VGPR, no spill). Registers available for more ILP at (512,4): ~10.
// Swapped QK (mfma(K,Q) -> S^T): softmax lane-local; pk2+permlane32_swap
// builds PV A-frags in-register. 2-phase dbuf with static buffer bases.
// REGISTER BUDGET (r4/r5/r7/r12): (512,4) = 128-cap unified pool.
// Tripwire = WRITE_SIZE >> 9 MB means spill: revert.
__global__ __launch_bounds__(512, 4) void k_attn(const bf16* __restrict__ Q,
                                                 const bf16* __restrict__ K,
                                                 const bf16* __restrict__ VT,
                                                 bf16* __restrict__ O) {
  __shared__ __align__(16) char smem[65536];
  int bid = blockIdx.x;
  int q128 = bid & 15;
  int h = (bid >> 4) & 15;
  int b = bid >> 8;
  int wv = threadIdx.x >> 6, lane = threadIdx.x & 63;
  int l31 = lane & 31, hi = lane >> 5;
  int qs = wv & 3, kh = wv >> 2;
  int q0 = q128 * 128 + qs * 32;

  const bf16* qrow =
      Q + ((size_t)(b * SEQ + q0 + l31) * NDIM + h * HD + hi * 8);
  bf16x8 aq[4];
#pragma unroll
  for (int f = 0; f < 4; f++) aq[f] = *(const bf16x8*)(qrow + f * 16);

  const int srow = lane >> 3, c16 = lane & 7;
  const int kvbeg = kh * (SEQ / 2);

  auto stage = [&](int bb, int t) {
    char* base = smem + bb * 32768 + kh * 16384;
    const int kv0 = kvbeg + t * 64;
#pragma unroll
    for (int j = 0; j < 4; j++) {
      int c = qs * 4 + j;
      if (c < 8) {
        const char* src = (const char*)K +
                          (size_t)(b * SEQ + kv0 + c * 8 + srow) * 128 +
                          ((c16 ^ srow) << 4);
        load_lds16(src, base + c * 1024);
      } else {
        const char* src = (const char*)VT +
                          (size_t)(b * 64 + (c - 8) * 8 + srow) * (SEQ * 2) +
                          (size_t)kv0 * 2 + ((c16 ^ srow) << 4);
        load_lds16(src, base + c * 1024);
      }
    }
  };

  f32x16 acc[2] = {};  // [dc]; lane: O[q=(r&3)+8(r>>2)+4hi][d=dc*32+l31]
  float lsum = 0.f;

  // compute one staged 64-kv tile at a STATIC buffer base (r11 form)
  auto compute = [&](char* Kl, char* Vl) {
#pragma unroll
    for (int kvb = 0; kvb < 2; kvb++) {
      bf16x8 kf[4];
#pragma unroll
      for (int f = 0; f < 4; f++)
        kf[f] = *(const bf16x8*)(Kl + (kvb * 32 + l31) * 128 +
                                 (((f * 2 + hi) ^ (l31 & 7)) << 4));
      f32x16 s = {};
      __builtin_amdgcn_s_setprio(1);
#pragma unroll
      for (int f = 0; f < 4; f++)
        s = __builtin_amdgcn_mfma_f32_32x32x16_bf16(kf[f], aq[f], s, 0, 0, 0);
      __builtin_amdgcn_s_setprio(0);
      float p[16];
#pragma unroll
      for (int i = 0; i < 16; i++) {
        p[i] = __builtin_amdgcn_exp2f(s[i]);
        lsum += p[i];
      }
#pragma unroll
      for (int n = 0; n < 2; n++) {
        uint32_t t0 = pk2(p[8 * n + 0], p[8 * n + 1]);
        uint32_t t1 = pk2(p[8 * n + 2], p[8 * n + 3]);
        uint32_t t2 = pk2(p[8 * n + 4], p[8 * n + 5]);
        uint32_t t3 = pk2(p[8 * n + 6], p[8 * n + 7]);
        u32x2 rA = __builtin_amdgcn_permlane32_swap(t0, t2, false, false);
        u32x2 rB = __builtin_amdgcn_permlane32_swap(t1, t3, false, false);
        union { uint32_t u[4]; bf16x8 v; } af;
        af.u[0] = rA[0]; af.u[1] = rB[0]; af.u[2] = rA[1]; af.u[3] = rB[1];
        __builtin_amdgcn_s_setprio(1);
#pragma unroll
        for (int dc = 0; dc < 2; dc++) {
          bf16x8 vf = *(const bf16x8*)(Vl + (dc * 32 + l31) * 128 +
                                       (((kvb * 4 + n * 2 + hi) ^ (l31 & 7))
                                        << 4));
          acc[dc] = __builtin_amdgcn_mfma_f32_32x32x16_bf16(af.v, vf, acc[dc],
                                                            0, 0, 0);
        }
        __builtin_amdgcn_s_setprio(0);
      }
    }
  };

  char* K0 = smem + kh * 16384;
  char* V0 = K0 + 8192;
  char* K1 = smem + 32768 + kh * 16384;
  char* V1 = K1 + 8192;

  stage(0, 0);
  __syncthreads();

#pragma unroll 1
  for (int t = 0; t < 16; t += 2) {
    stage(1, t + 1);            // always valid: t+1 <= 15
    compute(K0, V0);
    __syncthreads();
    if (t + 2 < 16) stage(0, t + 2);
    compute(K1, V1);
    __syncthreads();
  }

  lsum += __shfl_xor(lsum, 32, 64);

  // merge the two kv-halves: kh=1 writes partials, kh=0 adds + outputs.
  float* mb = (float*)smem;  // [4 qs][64 lanes][33 f32] = 33792 B
  if (kh == 1) {
    float* dst = mb + ((size_t)(qs * 64 + lane)) * 33;
#pragma unroll
    for (int dc = 0; dc < 2; dc++)
#pragma unroll
      for (int r = 0; r < 16; r++) dst[dc * 16 + r] = acc[dc][r];
    dst[32] = lsum;
  }
  __syncthreads();
  if (kh == 0) {
    const float* src = mb + ((size_t)(qs * 64 + lane)) * 33;
#pragma unroll
    for (int dc = 0; dc < 2; dc++)
#pragma unroll
      for (int r = 0; r < 16; r++) acc[dc][r] += src[dc * 16 + r];
    lsum += src[32];
#pragma unroll
    for (int r = 0; r < 16; r++) {
      int q_r = (r & 3) + 8 * (r >> 2) + 4 * hi;
      float ls = __shfl(lsum, q_r, 64);
      float rinv = 1.0f / ls;
#pragma unroll
      for (int dc = 0; dc < 2; dc++)
        O[(size_t)(b * SEQ + q0 + q_r) * NDIM + h * HD + dc * 32 + l31] =
            (bf16)(acc[dc][r] * rinv);
    }
  }
}

extern "C" void kernel_launch(void* const* d_in, const int* in_sizes, int n_in,
                              void* d_out, int out_size, void* d_ws, size_t ws_size,
                              hipStream_t stream) {
  const float* x = (const float*)d_in[0];
  const float* Wq = (const float*)d_in[1];
  const float* Wk = (const float*)d_in[2];
  const float* Wv = (const float*)d_in[3];
  const float* Wp = (const float*)d_in[4];
  const float* bp = (const float*)d_in[5];
  float* out = (float*)d_out;

  size_t off = 0;
  char* wsb = (char*)d_ws;
  auto alloc = [&](size_t bytes) {
    char* p = wsb + off;
    off += bytes;
    return p;
  };
  bf16* x_bf = (bf16*)alloc((size_t)4096 * 1024 * 2);
  bf16* wqkvT = (bf16*)alloc((size_t)1152 * 1024 * 2);  // [WqT;WkT;WvT]
  bf16* wpT = (bf16*)alloc((size_t)1024 * 1024 * 2);
  bf16* Qb = (bf16*)alloc((size_t)4096 * 1024 * 2);
  bf16* Kb = (bf16*)alloc((size_t)4096 * 64 * 2);
  bf16* VTb = (bf16*)alloc((size_t)2 * 64 * 2048 * 2);
  bf16* AOb = (bf16*)alloc((size_t)4096 * 1024 * 2);

  // fused prep: cvt (4096 blocks) + Wq (1024) + Wk (64) + Wv (64) + Wp (1024)
  k_prep<<<6272, 256, 0, stream>>>(x, Wq, Wk, Wv, Wp, x_bf, wqkvT, wpT);

  // fused Q/K/V projection: N = 1152 = 1024(Q) + 64(K) + 64(V)
  k_gemm<128, 64, 64, 32, 3><<<dim3(18, 32), 256, 0, stream>>>(
      x_bf, wqkvT, Qb, Kb, VTb, nullptr, 4096, 1152, 1024, QSCALE);

  k_attn<<<512, 512, 0, stream>>>(Qb, Kb, VTb, AOb);

  // output projection + bias, fp32 out
  k_gemm<128, 64, 64, 32, 2><<<dim3(16, 32), 256, 0, stream>>>(
      AOb, wpT, out, nullptr, nullptr, bp, 4096, 1024, 1024, 1.0f);
}

// Round 14
// 94.260 us; speedup vs baseline: 2.1588x; 1.0089x over previous
//
#include <hip/hip_runtime.h>
#include <hip/hip_bf16.h>
#include <stdint.h>

using bf16 = __bf16;
using bf16x4 = __attribute__((ext_vector_type(4))) __bf16;
using bf16x8 = __attribute__((ext_vector_type(8))) __bf16;
using f32x4 = __attribute__((ext_vector_type(4))) float;
using f32x16 = __attribute__((ext_vector_type(16))) float;
using u32x2 = __attribute__((ext_vector_type(2))) unsigned int;

static constexpr int SEQ = 2048;
static constexpr int NDIM = 1024;
static constexpr int NHEAD = 16;
static constexpr int HD = 64;
// fold softmax scale and log2(e) into Q so scores are already in log2 domain
static constexpr float QSCALE = 0.125f * 1.4426950408889634f;

__device__ __forceinline__ void load_lds16(const void* g, void* l) {
  __builtin_amdgcn_global_load_lds(
      (const __attribute__((address_space(1))) void*)g,
      (__attribute__((address_space(3))) void*)l, 16, 0, 0);
}

// pack two fp32 -> one u32 of two bf16 (lo = a, hi = b)
__device__ __forceinline__ uint32_t pk2(float a, float b) {
  uint16_t ua = __builtin_bit_cast(uint16_t, (bf16)a);
  uint16_t ub = __builtin_bit_cast(uint16_t, (bf16)b);
  return (uint32_t)ua | ((uint32_t)ub << 16);
}

// ---- fused prep: x fp32->bf16 (blocks 0..4095) + 4 weight transposes ------
// (r12 win: was 5 dispatches; fusing removed 4 launch gaps/tails, ~12 us)
__global__ __launch_bounds__(256) void k_prep(const float* __restrict__ x,
                                              const float* __restrict__ Wq,
                                              const float* __restrict__ Wk,
                                              const float* __restrict__ Wv,
                                              const float* __restrict__ Wp,
                                              bf16* __restrict__ x_bf,
                                              bf16* __restrict__ wqkvT,
                                              bf16* __restrict__ wpT) {
  __shared__ float t[32][33];
  int bid = blockIdx.x;
  if (bid < 4096) {  // cvt: 4096 blocks x 256 thr x 4 elems = 4096*1024
    int i = (bid * 256 + threadIdx.x) * 4;
    float4 v = *(const float4*)(x + i);
    bf16x4 o;
    o[0] = (bf16)v.x; o[1] = (bf16)v.y; o[2] = (bf16)v.z; o[3] = (bf16)v.w;
    *(bf16x4*)(x_bf + i) = o;
    return;
  }
  const float* W; bf16* WT; int N; int idx;
  if (bid < 5120)      { W = Wq; WT = wqkvT;                         N = 1024; idx = bid - 4096; }
  else if (bid < 5184) { W = Wk; WT = wqkvT + (size_t)1024 * 1024;   N = 64;   idx = bid - 5120; }
  else if (bid < 5248) { W = Wv; WT = wqkvT + (size_t)1088 * 1024;   N = 64;   idx = bid - 5184; }
  else                 { W = Wp; WT = wpT;                           N = 1024; idx = bid - 5248; }
  const int nb = N / 32;
  const int n0 = (idx % nb) * 32, k0 = (idx / nb) * 32;
  const int tx = threadIdx.x & 31, ty = threadIdx.x >> 5;  // 32 x 8
#pragma unroll
  for (int i = 0; i < 4; i++)
    t[ty + 8 * i][tx] = W[(size_t)(k0 + ty + 8 * i) * N + n0 + tx];
  __syncthreads();
#pragma unroll
  for (int i = 0; i < 4; i++)
    WT[(size_t)(n0 + ty + 8 * i) * 1024 + k0 + tx] = (bf16)t[tx][ty + 8 * i];
}

// ---------------- bf16 GEMM: C = A(MxK) @ BT(NxK)^T ----------------
// MODE 2: C fp32 + bias                           (output projection)
// MODE 3: fused QKV: col<1024 -> Q bf16 * scale; col in [1024,1088) -> K bf16
//         (C2); col >= 1088 -> V bf16 stored transposed per batch (C3)
// 128x64 tile (r11 win). r14: 2-phase LDS double-buffer (T3 minimum, same
// pattern as attn r10's +10%): stage(buf^1, kt+64) issued BEFORE compute(buf),
// ONE barrier per K-step -- previous form exposed global_load_lds latency at
// every K-step between two barriers. LDS 48KB -> 3 blocks/CU LDS-wise.
// K must be a multiple of 128 (16 steps, unroll-by-2): holds (K=1024).
template <int BM, int BN, int WM, int WN, int MODE>
__global__ __launch_bounds__(256) void k_gemm(const bf16* __restrict__ A,
                                              const bf16* __restrict__ BT,
                                              void* __restrict__ C,
                                              void* __restrict__ C2,
                                              void* __restrict__ C3,
                                              const float* __restrict__ bias,
                                              int M, int N, int K, float scale) {
  __shared__ __align__(16) char As[2][BM * 128];
  __shared__ __align__(16) char Bs[2][BN * 128];
  const int lane = threadIdx.x & 63;
  const int wv = threadIdx.x >> 6;
  constexpr int NWC = BN / WN;
  const int wr = wv / NWC, wc = wv % NWC;
  const int g = lane >> 4, l15 = lane & 15;
  const int m0 = blockIdx.y * BM, n0 = blockIdx.x * BN;
  constexpr int MI = WM / 16, NI = WN / 16;

  f32x4 acc[MI][NI] = {};

  const int srow = lane >> 3;   // staging row within 8-row chunk
  const int c16 = lane & 7;     // staging 16B-column within row

  auto stage = [&](char* Ad, char* Bd, int kt) {
#pragma unroll
    for (int j = wv; j < BM / 8; j += 4) {
      int row = j * 8 + srow;
      const char* src = (const char*)A + (size_t)(m0 + row) * (K * 2) + kt * 2 +
                        ((c16 ^ (row & 7)) << 4);
      load_lds16(src, Ad + j * 1024);
    }
#pragma unroll
    for (int j = wv; j < BN / 8; j += 4) {
      int row = j * 8 + srow;
      const char* src = (const char*)BT + (size_t)(n0 + row) * (K * 2) + kt * 2 +
                        ((c16 ^ (row & 7)) << 4);
      load_lds16(src, Bd + j * 1024);
    }
  };

  auto compute = [&](const char* Ab, const char* Bb) {
#pragma unroll
    for (int kk = 0; kk < 2; kk++) {
      bf16x8 af[MI], bfr[NI];
#pragma unroll
      for (int mi = 0; mi < MI; mi++) {
        int row = wr * WM + mi * 16 + l15;
        af[mi] = *(const bf16x8*)(Ab + row * 128 + (((kk * 4 + g) ^ (row & 7)) << 4));
      }
#pragma unroll
      for (int ni = 0; ni < NI; ni++) {
        int row = wc * WN + ni * 16 + l15;
        bfr[ni] = *(const bf16x8*)(Bb + row * 128 + (((kk * 4 + g) ^ (row & 7)) << 4));
      }
#pragma unroll
      for (int mi = 0; mi < MI; mi++)
#pragma unroll
        for (int ni = 0; ni < NI; ni++)
          acc[mi][ni] = __builtin_amdgcn_mfma_f32_16x16x32_bf16(af[mi], bfr[ni],
                                                                acc[mi][ni], 0, 0, 0);
    }
  };

  stage(As[0], Bs[0], 0);
  __syncthreads();
  for (int kt = 0; kt < K; kt += 128) {
    stage(As[1], Bs[1], kt + 64);           // always valid: kt+64 < K
    compute(As[0], Bs[0]);
    __syncthreads();
    if (kt + 128 < K) stage(As[0], Bs[0], kt + 128);
    compute(As[1], Bs[1]);
    __syncthreads();
  }

#pragma unroll
  for (int mi = 0; mi < MI; mi++)
#pragma unroll
    for (int ni = 0; ni < NI; ni++) {
      int col = n0 + wc * WN + ni * 16 + l15;
      int rowb = m0 + wr * WM + mi * 16 + g * 4;
      if (MODE == 2) {
        float bv = bias[col];
#pragma unroll
        for (int r = 0; r < 4; r++)
          ((float*)C)[(size_t)(rowb + r) * N + col] = acc[mi][ni][r] + bv;
      } else {  // MODE 3: fused QKV epilogue
        if (col < 1024) {
#pragma unroll
          for (int r = 0; r < 4; r++)
            ((bf16*)C)[(size_t)(rowb + r) * 1024 + col] =
                (bf16)(acc[mi][ni][r] * scale);
        } else if (col < 1088) {
#pragma unroll
          for (int r = 0; r < 4; r++)
            ((bf16*)C2)[(size_t)(rowb + r) * 64 + (col - 1024)] =
                (bf16)acc[mi][ni][r];
        } else {
#pragma unroll
          for (int r = 0; r < 4; r++) {
            int m = rowb + r;
            ((bf16*)C3)[((size_t)((m >> 11) * 64 + (col - 1088))) * 2048 +
                        (m & 2047)] = (bf16)acc[mi][ni][r];
          }
        }
      }
    }
}

// ---- fused attention: 8-wave blocks, shared LDS K/V tiles, 2-phase dbuf ----
// grid = B * H * (SEQ/128) = 512 blocks; block = 8 waves = 4 qsub x 2 kvhalf.
// Measured-best form (51.5 us, 64 arch VGPR, no spill). STRUCTURAL PLATEAU:
// unified live set ~96 regs rounds to the 128-reg allocation quantum (m69) ->
// 16 waves/CU cap; LDS 64KB -> 2 blocks/CU; every escape (kv-split-4 + global
// merge, more reg ILP) costs >= its gain (r7/r12 spills, merge ~14 us traffic).
// Swapped QK (mfma(K,Q) -> S^T): softmax lane-local; pk2+permlane32_swap
// builds PV A-frags in-register. 2-phase dbuf with static buffer bases.
// REGISTER BUDGET (r4/r5/r7/r12): (512,4) = 128-cap unified pool.
// Tripwire = WRITE_SIZE >> 9 MB means spill: revert.
__global__ __launch_bounds__(512, 4) void k_attn(const bf16* __restrict__ Q,
                                                 const bf16* __restrict__ K,
                                                 const bf16* __restrict__ VT,
                                                 bf16* __restrict__ O) {
  __shared__ __align__(16) char smem[65536];
  int bid = blockIdx.x;
  int q128 = bid & 15;
  int h = (bid >> 4) & 15;
  int b = bid >> 8;
  int wv = threadIdx.x >> 6, lane = threadIdx.x & 63;
  int l31 = lane & 31, hi = lane >> 5;
  int qs = wv & 3, kh = wv >> 2;
  int q0 = q128 * 128 + qs * 32;

  const bf16* qrow =
      Q + ((size_t)(b * SEQ + q0 + l31) * NDIM + h * HD + hi * 8);
  bf16x8 aq[4];
#pragma unroll
  for (int f = 0; f < 4; f++) aq[f] = *(const bf16x8*)(qrow + f * 16);

  const int srow = lane >> 3, c16 = lane & 7;
  const int kvbeg = kh * (SEQ / 2);

  auto stage = [&](int bb, int t) {
    char* base = smem + bb * 32768 + kh * 16384;
    const int kv0 = kvbeg + t * 64;
#pragma unroll
    for (int j = 0; j < 4; j++) {
      int c = qs * 4 + j;
      if (c < 8) {
        const char* src = (const char*)K +
                          (size_t)(b * SEQ + kv0 + c * 8 + srow) * 128 +
                          ((c16 ^ srow) << 4);
        load_lds16(src, base + c * 1024);
      } else {
        const char* src = (const char*)VT +
                          (size_t)(b * 64 + (c - 8) * 8 + srow) * (SEQ * 2) +
                          (size_t)kv0 * 2 + ((c16 ^ srow) << 4);
        load_lds16(src, base + c * 1024);
      }
    }
  };

  f32x16 acc[2] = {};  // [dc]; lane: O[q=(r&3)+8(r>>2)+4hi][d=dc*32+l31]
  float lsum = 0.f;

  // compute one staged 64-kv tile at a STATIC buffer base (r11 form)
  auto compute = [&](char* Kl, char* Vl) {
#pragma unroll
    for (int kvb = 0; kvb < 2; kvb++) {
      bf16x8 kf[4];
#pragma unroll
      for (int f = 0; f < 4; f++)
        kf[f] = *(const bf16x8*)(Kl + (kvb * 32 + l31) * 128 +
                                 (((f * 2 + hi) ^ (l31 & 7)) << 4));
      f32x16 s = {};
      __builtin_amdgcn_s_setprio(1);
#pragma unroll
      for (int f = 0; f < 4; f++)
        s = __builtin_amdgcn_mfma_f32_32x32x16_bf16(kf[f], aq[f], s, 0, 0, 0);
      __builtin_amdgcn_s_setprio(0);
      float p[16];
#pragma unroll
      for (int i = 0; i < 16; i++) {
        p[i] = __builtin_amdgcn_exp2f(s[i]);
        lsum += p[i];
      }
#pragma unroll
      for (int n = 0; n < 2; n++) {
        uint32_t t0 = pk2(p[8 * n + 0], p[8 * n + 1]);
        uint32_t t1 = pk2(p[8 * n + 2], p[8 * n + 3]);
        uint32_t t2 = pk2(p[8 * n + 4], p[8 * n + 5]);
        uint32_t t3 = pk2(p[8 * n + 6], p[8 * n + 7]);
        u32x2 rA = __builtin_amdgcn_permlane32_swap(t0, t2, false, false);
        u32x2 rB = __builtin_amdgcn_permlane32_swap(t1, t3, false, false);
        union { uint32_t u[4]; bf16x8 v; } af;
        af.u[0] = rA[0]; af.u[1] = rB[0]; af.u[2] = rA[1]; af.u[3] = rB[1];
        __builtin_amdgcn_s_setprio(1);
#pragma unroll
        for (int dc = 0; dc < 2; dc++) {
          bf16x8 vf = *(const bf16x8*)(Vl + (dc * 32 + l31) * 128 +
                                       (((kvb * 4 + n * 2 + hi) ^ (l31 & 7))
                                        << 4));
          acc[dc] = __builtin_amdgcn_mfma_f32_32x32x16_bf16(af.v, vf, acc[dc],
                                                            0, 0, 0);
        }
        __builtin_amdgcn_s_setprio(0);
      }
    }
  };

  char* K0 = smem + kh * 16384;
  char* V0 = K0 + 8192;
  char* K1 = smem + 32768 + kh * 16384;
  char* V1 = K1 + 8192;

  stage(0, 0);
  __syncthreads();

#pragma unroll 1
  for (int t = 0; t < 16; t += 2) {
    stage(1, t + 1);            // always valid: t+1 <= 15
    compute(K0, V0);
    __syncthreads();
    if (t + 2 < 16) stage(0, t + 2);
    compute(K1, V1);
    __syncthreads();
  }

  lsum += __shfl_xor(lsum, 32, 64);

  // merge the two kv-halves: kh=1 writes partials, kh=0 adds + outputs.
  float* mb = (float*)smem;  // [4 qs][64 lanes][33 f32] = 33792 B
  if (kh == 1) {
    float* dst = mb + ((size_t)(qs * 64 + lane)) * 33;
#pragma unroll
    for (int dc = 0; dc < 2; dc++)
#pragma unroll
      for (int r = 0; r < 16; r++) dst[dc * 16 + r] = acc[dc][r];
    dst[32] = lsum;
  }
  __syncthreads();
  if (kh == 0) {
    const float* src = mb + ((size_t)(qs * 64 + lane)) * 33;
#pragma unroll
    for (int dc = 0; dc < 2; dc++)
#pragma unroll
      for (int r = 0; r < 16; r++) acc[dc][r] += src[dc * 16 + r];
    lsum += src[32];
#pragma unroll
    for (int r = 0; r < 16; r++) {
      int q_r = (r & 3) + 8 * (r >> 2) + 4 * hi;
      float ls = __shfl(lsum, q_r, 64);
      float rinv = 1.0f / ls;
#pragma unroll
      for (int dc = 0; dc < 2; dc++)
        O[(size_t)(b * SEQ + q0 + q_r) * NDIM + h * HD + dc * 32 + l31] =
            (bf16)(acc[dc][r] * rinv);
    }
  }
}

extern "C" void kernel_launch(void* const* d_in, const int* in_sizes, int n_in,
                              void* d_out, int out_size, void* d_ws, size_t ws_size,
                              hipStream_t stream) {
  const float* x = (const float*)d_in[0];
  const float* Wq = (const float*)d_in[1];
  const float* Wk = (const float*)d_in[2];
  const float* Wv = (const float*)d_in[3];
  const float* Wp = (const float*)d_in[4];
  const float* bp = (const float*)d_in[5];
  float* out = (float*)d_out;

  size_t off = 0;
  char* wsb = (char*)d_ws;
  auto alloc = [&](size_t bytes) {
    char* p = wsb + off;
    off += bytes;
    return p;
  };
  bf16* x_bf = (bf16*)alloc((size_t)4096 * 1024 * 2);
  bf16* wqkvT = (bf16*)alloc((size_t)1152 * 1024 * 2);  // [WqT;WkT;WvT]
  bf16* wpT = (bf16*)alloc((size_t)1024 * 1024 * 2);
  bf16* Qb = (bf16*)alloc((size_t)4096 * 1024 * 2);
  bf16* Kb = (bf16*)alloc((size_t)4096 * 64 * 2);
  bf16* VTb = (bf16*)alloc((size_t)2 * 64 * 2048 * 2);
  bf16* AOb = (bf16*)alloc((size_t)4096 * 1024 * 2);

  // fused prep: cvt (4096 blocks) + Wq (1024) + Wk (64) + Wv (64) + Wp (1024)
  k_prep<<<6272, 256, 0, stream>>>(x, Wq, Wk, Wv, Wp, x_bf, wqkvT, wpT);

  // fused Q/K/V projection: N = 1152 = 1024(Q) + 64(K) + 64(V)
  k_gemm<128, 64, 64, 32, 3><<<dim3(18, 32), 256, 0, stream>>>(
      x_bf, wqkvT, Qb, Kb, VTb, nullptr, 4096, 1152, 1024, QSCALE);

  k_attn<<<512, 512, 0, stream>>>(Qb, Kb, VTb, AOb);

  // output projection + bias, fp32 out
  k_gemm<128, 64, 64, 32, 2><<<dim3(16, 32), 256, 0, stream>>>(
      AOb, wpT, out, nullptr, nullptr, bp, 4096, 1024, 1024, 1.0f);
}